// Round 7
// baseline (217.729 us; speedup 1.0000x reference)
//
#include <hip/hip_runtime.h>
#include <math.h>

typedef unsigned short u16;
typedef unsigned int u32;
typedef unsigned long long u64;
typedef short bf16x8 __attribute__((ext_vector_type(8)));
typedef float f32x4 __attribute__((ext_vector_type(4)));

constexpr int NB = 2, NS = 2048, ND = 512, NH = 8, NHD = 64;
constexpr int NKTOP = 307, NHWIN = 16, NRC = 16;
constexpr int NILIST = 320;        // 20 tiles of 16 (padded with -1)
constexpr int NSPAR = NS - NKTOP;  // 1741 non-important rows (exact: rank is a permutation)
constexpr int NSPAD = 1744;        // padded to multiple of 4
constexpr int NCHUNK = 8;          // key-split factor for important-row attention
constexpr int LDSPAD = 40;         // 80B row stride for 32-k tiles
constexpr int LDSK64 = 72;         // 144B row stride for 64-k tiles
constexpr int PSTR = 72;           // P-tile row stride (16 rows x 64 keys)
constexpr int NSBLK = (NSPAD / 4) * NH * NB;                    // 6976 sparse blocks (4 waves each)
constexpr int NIBLK = (NILIST / 16) * NCHUNK * (NB * NH) / 4;   // 640 imp blocks (4 waves each)

__device__ __forceinline__ u16 f2bf(float f) {
  u32 u = __builtin_bit_cast(u32, f);
  u32 r = (u + 0x7FFFu + ((u >> 16) & 1u)) >> 16;  // RNE
  return (u16)r;
}
__device__ __forceinline__ float bf2f(short v) {
  return __builtin_bit_cast(float, (u32)(u16)v << 16);
}
// wave-local LDS fence: per-wave DS ops retire in order; lgkmcnt(0) makes this wave's
// ds_writes visible to its own subsequent ds_reads (cross-lane within wave). No block barrier.
__device__ __forceinline__ void wave_lds_fence() {
  __builtin_amdgcn_s_waitcnt(0xC07F);  // lgkmcnt(0), vmcnt/expcnt unconstrained
  __builtin_amdgcn_wave_barrier();
}

// -------- fused prep: scorer (blocks 0..255) + weight transpose (blocks 256..767) --------
// scorer: part[row][ny] = relu(x@Ws1+bs1).Ws2 over 64-col slice (fp32).
// sigmoid and bs2 are strictly monotone / constant -> ranking on raw logits is identical.
__global__ __launch_bounds__(256) void csa_prep(const float* __restrict__ W0, const float* __restrict__ W1,
                                                const float* __restrict__ W2, const float* __restrict__ W3,
                                                u16* __restrict__ wt, const float* __restrict__ x,
                                                const float* __restrict__ Ws1, const float* __restrict__ bs1,
                                                const float* __restrict__ Ws2, float* __restrict__ part) {
  __shared__ float sh[2 * 32 * 68];  // 17.4 KB: scorer As+Bs; cvt tile (64x33) fits too
  const int tid = threadIdx.x;
  if (blockIdx.x < 256) {
    // ---- scorer 64x64 tile ----
    const int m0 = (blockIdx.x & 63) * 64, n0 = (blockIdx.x >> 6) * 64;
    float(*As)[68] = (float(*)[68])sh;
    float(*Bs)[68] = (float(*)[68])(sh + 32 * 68);
    const int ty = tid >> 4, tx = tid & 15;
    float acc[4][4] = {};
    const int arow = tid & 63, aks = (tid >> 6) * 8;
    const int bk = tid >> 3, bc = (tid & 7) * 8;
    for (int k0 = 0; k0 < ND; k0 += 32) {
      __syncthreads();
      {
        float4 a0 = *(const float4*)(&x[(size_t)(m0 + arow) * ND + k0 + aks]);
        float4 a1 = *(const float4*)(&x[(size_t)(m0 + arow) * ND + k0 + aks + 4]);
        As[aks + 0][arow] = a0.x; As[aks + 1][arow] = a0.y;
        As[aks + 2][arow] = a0.z; As[aks + 3][arow] = a0.w;
        As[aks + 4][arow] = a1.x; As[aks + 5][arow] = a1.y;
        As[aks + 6][arow] = a1.z; As[aks + 7][arow] = a1.w;
      }
      *(float4*)(&Bs[bk][bc]) = *(const float4*)(&Ws1[(size_t)(k0 + bk) * 256 + n0 + bc]);
      *(float4*)(&Bs[bk][bc + 4]) = *(const float4*)(&Ws1[(size_t)(k0 + bk) * 256 + n0 + bc + 4]);
      __syncthreads();
      for (int k = 0; k < 32; k++) {
        float4 av = *(const float4*)(&As[k][ty * 4]);
        float4 bv = *(const float4*)(&Bs[k][tx * 4]);
        float aa[4] = {av.x, av.y, av.z, av.w};
        float bb[4] = {bv.x, bv.y, bv.z, bv.w};
        for (int i = 0; i < 4; i++)
          for (int j = 0; j < 4; j++)
            acc[i][j] += aa[i] * bb[j];
      }
    }
    float4 w2 = *(const float4*)(&Ws2[n0 + tx * 4]);
    float4 b1 = *(const float4*)(&bs1[n0 + tx * 4]);
    for (int i = 0; i < 4; i++) {
      float p = fmaxf(acc[i][0] + b1.x, 0.f) * w2.x + fmaxf(acc[i][1] + b1.y, 0.f) * w2.y +
                fmaxf(acc[i][2] + b1.z, 0.f) * w2.z + fmaxf(acc[i][3] + b1.w, 0.f) * w2.w;
      for (int off = 1; off < 16; off <<= 1) p += __shfl_xor(p, off, 64);
      if (tx == 0) part[(size_t)(m0 + ty * 4 + i) * 4 + (blockIdx.x >> 6)] = p;
    }
  } else {
    // ---- weight transpose: W[K][N] fp32 -> Wt[N][K] bf16, 128B packed writes ----
    const int cb = blockIdx.x - 256;
    const int w = cb >> 7;
    const int kb = ((cb & 127) >> 4) * 64;
    const int nb = (cb & 15) * 32;
    const float* src = (w == 0) ? W0 : (w == 1) ? W1 : (w == 2) ? W2 : W3;
    float(*tile)[33] = (float(*)[33])sh;
    int tx = tid & 31, ty = tid >> 5;
    for (int i = ty; i < 64; i += 8) tile[i][tx] = src[(size_t)(kb + i) * ND + nb + tx];
    __syncthreads();
    u16* dst = wt + (size_t)w * ND * ND;
    for (int n = ty; n < 32; n += 8) {
      u32 pk = (u32)f2bf(tile[2 * tx][n]) | ((u32)f2bf(tile[2 * tx + 1][n]) << 16);
      *(u32*)(&dst[(size_t)(nb + n) * ND + kb + 2 * tx]) = pk;
    }
  }
}

// -------- exact top-k on logits (lax.top_k tie semantics: lower index wins), wave per 2 rows --------
__global__ __launch_bounds__(256) void csa_rank(const float* __restrict__ part, int* __restrict__ rowimp) {
  __shared__ float vals[NS];
  const int b = blockIdx.y;
  {
    int t8 = threadIdx.x * 8;
    for (int e = 0; e < 8; e++) {
      float4 pp = *(const float4*)(&part[(size_t)(b * NS + t8 + e) * 4]);
      vals[t8 + e] = (pp.x + pp.y) + (pp.z + pp.w);  // fixed order -> deterministic
    }
  }
  __syncthreads();
  const int wave = threadIdx.x >> 6, lane = threadIdx.x & 63;
  const int s0 = blockIdx.x * 8 + wave * 2;  // two rows per wave
  const int s1 = s0 + 1;
  const float v0 = vals[s0], v1 = vals[s1];
  int r0 = 0, r1 = 0;
  for (int t = lane; t < NS; t += 64) {
    float u = vals[t];
    r0 += (int)((u > v0) | ((u == v0) & (t < s0)));
    r1 += (int)((u > v1) | ((u == v1) & (t < s1)));
  }
  for (int off = 1; off < 64; off <<= 1) {
    r0 += __shfl_xor(r0, off, 64);
    r1 += __shfl_xor(r1, off, 64);
  }
  if (lane == 0) {
    rowimp[b * NS + s0] = (r0 < NKTOP) ? 1 : 0;
    rowimp[b * NS + s1] = (r1 < NKTOP) ? 1 : 0;
  }
}

// -------- compact important rows (and complement) into sorted lists --------
__global__ __launch_bounds__(256) void csa_ilist(const int* __restrict__ rowimp, int* __restrict__ ilist,
                                                 int* __restrict__ nlist) {
  __shared__ int cs[256];
  int b = blockIdx.x, t = threadIdx.x;
  int flags[8], sum = 0;
  for (int k = 0; k < 8; k++) {
    flags[k] = rowimp[b * NS + t * 8 + k];
    sum += flags[k];
  }
  cs[t] = sum;
  __syncthreads();
  for (int off = 1; off < 256; off <<= 1) {
    int v = (t >= off) ? cs[t - off] : 0;
    __syncthreads();
    cs[t] += v;
    __syncthreads();
  }
  int pos = cs[t] - sum;  // important rows before t*8
  for (int k = 0; k < 8; k++) {
    int r = t * 8 + k;
    if (flags[k]) ilist[b * NILIST + pos++] = r;
    else nlist[b * NSPAD + (r - pos)] = r;  // r - pos = non-important rows before r
  }
  if (t < NILIST - NKTOP) ilist[b * NILIST + NKTOP + t] = -1;
  if (t < NSPAD - NSPAR) nlist[b * NSPAD + NSPAR + t] = -1;
}

// -------- fused QKV projection: fp32 x staged->bf16, MFMA 128x64 tile, N=1536 --------
__global__ __launch_bounds__(256) void csa_gemm_qkv(const float* __restrict__ x, const u16* __restrict__ Bt,
                                                    const float* __restrict__ bq, const float* __restrict__ bk,
                                                    const float* __restrict__ bv, u16* __restrict__ qb,
                                                    u16* __restrict__ kb, u16* __restrict__ vtb,
                                                    u16* __restrict__ vb) {
  __shared__ __attribute__((aligned(16))) u16 As[128 * LDSPAD];
  __shared__ __attribute__((aligned(16))) u16 Bs[64 * LDSPAD];
  const int tid = threadIdx.x;
  const int wave = tid >> 6, lane = tid & 63;
  const int quad = lane >> 4, col = lane & 15;
  const int m0 = blockIdx.x * 128;
  const int n0 = blockIdx.y * 64;
  const f32x4 zf = {0.f, 0.f, 0.f, 0.f};
  f32x4 acc[2][4] = {{zf, zf, zf, zf}, {zf, zf, zf, zf}};
  const int sar = tid >> 1, sak = (tid & 1) * 16;  // A: 128 rows x 32 k
  const int sbr = tid >> 2, sbk = (tid & 3) * 8;   // B: 64 rows x 32 k
  for (int k0 = 0; k0 < ND; k0 += 32) {
    __syncthreads();
    {
      const float* xp = &x[(size_t)(m0 + sar) * ND + k0 + sak];
      float4 v0 = *(const float4*)(xp), v1 = *(const float4*)(xp + 4);
      float4 v2 = *(const float4*)(xp + 8), v3 = *(const float4*)(xp + 12);
      u32 w0 = (u32)f2bf(v0.x) | ((u32)f2bf(v0.y) << 16);
      u32 w1 = (u32)f2bf(v0.z) | ((u32)f2bf(v0.w) << 16);
      u32 w2 = (u32)f2bf(v1.x) | ((u32)f2bf(v1.y) << 16);
      u32 w3 = (u32)f2bf(v1.z) | ((u32)f2bf(v1.w) << 16);
      u32 w4 = (u32)f2bf(v2.x) | ((u32)f2bf(v2.y) << 16);
      u32 w5 = (u32)f2bf(v2.z) | ((u32)f2bf(v2.w) << 16);
      u32 w6 = (u32)f2bf(v3.x) | ((u32)f2bf(v3.y) << 16);
      u32 w7 = (u32)f2bf(v3.z) | ((u32)f2bf(v3.w) << 16);
      u32* ap = (u32*)&As[sar * LDSPAD + sak];
      ap[0] = w0; ap[1] = w1; ap[2] = w2; ap[3] = w3;
      ap[4] = w4; ap[5] = w5; ap[6] = w6; ap[7] = w7;
    }
    *(uint4*)(&Bs[sbr * LDSPAD + sbk]) = *(const uint4*)(&Bt[(size_t)(n0 + sbr) * ND + k0 + sbk]);
    __syncthreads();
    bf16x8 af0 = *(const bf16x8*)(&As[(wave * 32 + col) * LDSPAD + quad * 8]);
    bf16x8 af1 = *(const bf16x8*)(&As[(wave * 32 + 16 + col) * LDSPAD + quad * 8]);
    for (int c = 0; c < 4; c++) {
      bf16x8 bfr = *(const bf16x8*)(&Bs[(c * 16 + col) * LDSPAD + quad * 8]);
      acc[0][c] = __builtin_amdgcn_mfma_f32_16x16x32_bf16(af0, bfr, acc[0][c], 0, 0, 0);
      acc[1][c] = __builtin_amdgcn_mfma_f32_16x16x32_bf16(af1, bfr, acc[1][c], 0, 0, 0);
    }
  }
  const int w = n0 >> 9;  // 0=Q 1=K 2=V (uniform per block; 64-tiles align in 512 regions)
  const float* bias = (w == 0) ? bq : (w == 1) ? bk : bv;
  for (int c = 0; c < 4; c++) {
    const int ng = n0 + c * 16 + col;
    const int nn = ng & 511, hh = nn >> 6, hd = nn & 63;
    const float bvv = bias[nn];
    for (int r = 0; r < 2; r++) {
      for (int rr = 0; rr < 4; rr++) {
        const int m = m0 + wave * 32 + r * 16 + quad * 4 + rr;
        const int bb = m >> 11, s = m & (NS - 1);
        u16 v16 = f2bf(acc[r][c][rr] + bvv);
        if (w == 0) qb[((size_t)(bb * NH + hh) * NS + s) * NHD + hd] = v16;
        else if (w == 1) kb[((size_t)(bb * NH + hh) * NS + s) * NHD + hd] = v16;
        else {
          vtb[((size_t)(bb * NH + hh) * NHD + hd) * NS + s] = v16;
          vb[((size_t)(bb * NH + hh) * NS + s) * NHD + hd] = v16;
        }
      }
    }
  }
}

// -------- output projection: bf16 MFMA 64x64 tile, K=64 stages, fp32 out --------
__global__ __launch_bounds__(256) void csa_gemm_out(const u16* __restrict__ A, const u16* __restrict__ Bt,
                                                    const float* __restrict__ bias, float* __restrict__ outp) {
  __shared__ __attribute__((aligned(16))) u16 As[64 * LDSK64];
  __shared__ __attribute__((aligned(16))) u16 Bs[64 * LDSK64];
  const int tid = threadIdx.x;
  const int wave = tid >> 6, lane = tid & 63;
  const int quad = lane >> 4, col = lane & 15;
  const int m0 = blockIdx.x * 64;
  const int n0 = blockIdx.y * 64;
  const f32x4 zf = {0.f, 0.f, 0.f, 0.f};
  f32x4 acc[4] = {zf, zf, zf, zf};
  const int sr = tid >> 2, sk = (tid & 3) * 16;  // 64 rows x 64 k, 16 u16/thread
  for (int k0 = 0; k0 < ND; k0 += 64) {
    __syncthreads();
    *(uint4*)(&As[sr * LDSK64 + sk]) = *(const uint4*)(&A[(size_t)(m0 + sr) * ND + k0 + sk]);
    *(uint4*)(&As[sr * LDSK64 + sk + 8]) = *(const uint4*)(&A[(size_t)(m0 + sr) * ND + k0 + sk + 8]);
    *(uint4*)(&Bs[sr * LDSK64 + sk]) = *(const uint4*)(&Bt[(size_t)(n0 + sr) * ND + k0 + sk]);
    *(uint4*)(&Bs[sr * LDSK64 + sk + 8]) = *(const uint4*)(&Bt[(size_t)(n0 + sr) * ND + k0 + sk + 8]);
    __syncthreads();
    bf16x8 af0 = *(const bf16x8*)(&As[(wave * 16 + col) * LDSK64 + quad * 8]);
    bf16x8 af1 = *(const bf16x8*)(&As[(wave * 16 + col) * LDSK64 + 32 + quad * 8]);
    for (int nt = 0; nt < 4; nt++) {
      bf16x8 bf0 = *(const bf16x8*)(&Bs[(nt * 16 + col) * LDSK64 + quad * 8]);
      bf16x8 bf1 = *(const bf16x8*)(&Bs[(nt * 16 + col) * LDSK64 + 32 + quad * 8]);
      acc[nt] = __builtin_amdgcn_mfma_f32_16x16x32_bf16(af0, bf0, acc[nt], 0, 0, 0);
      acc[nt] = __builtin_amdgcn_mfma_f32_16x16x32_bf16(af1, bf1, acc[nt], 0, 0, 0);
    }
  }
  for (int nt = 0; nt < 4; nt++) {
    const int n = n0 + nt * 16 + col;
    const float bvv = bias[n];
    for (int r = 0; r < 4; r++) {
      const int m = m0 + wave * 16 + quad * 4 + r;
      outp[(size_t)m * ND + n] = acc[nt][r] + bvv;
    }
  }
}

// -------- fused attention: sparse blocks [0, NSBLK) + important blocks [NSBLK, NSBLK+NIBLK) --------
// Both paths are wave-independent (per-wave LDS regions, wave_lds_fence instead of __syncthreads),
// so MFMA-bound imp waves and VALU-bound sparse waves co-schedule on the same CUs (m114 overlap).
__global__ __launch_bounds__(256) void csa_attn(const u16* __restrict__ qb, const u16* __restrict__ kb,
                                                const u16* __restrict__ vb, const u16* __restrict__ vtb,
                                                const int* __restrict__ ilist, const int* __restrict__ nlist,
                                                const int* __restrict__ rand_idx, float* __restrict__ pbuf,
                                                u16* __restrict__ attnb) {
  __shared__ __attribute__((aligned(16))) char smem[4 * 16 * PSTR * 2];  // 9216 B (imp) > 1568 B (sparse)
  const int wave = threadIdx.x >> 6, lane = threadIdx.x & 63;
  const f32x4 zf = {0.f, 0.f, 0.f, 0.f};

  if (blockIdx.x < NSBLK) {
    // ================= sparse rows: window + deduped random + diag, 1 wave per (row, head) ========
    u16* ql = (u16*)smem + wave * 64;                   // 512 B total
    float* pl = (float*)(smem + 512) + wave * 33;       // 528 B
    int* jl = (int*)(smem + 1040) + wave * 33;          // 528 B
    const int bx = blockIdx.x % (NSPAD / 4);
    const int rem = blockIdx.x / (NSPAD / 4);
    const int h = rem & 7, b = rem >> 3;
    const int slot = bx * 4 + wave;
    const int i = nlist[b * NSPAD + slot];  // -1 for the 3 pad slots
    const int iv = (i < 0) ? 0 : i;

    const u16* qrow = qb + ((size_t)(b * NH + h) * NS + iv) * NHD;
    const u16* kbase = kb + (size_t)(b * NH + h) * NS * NHD;
    const u16* vbase = vb + (size_t)(b * NH + h) * NS * NHD;

    if (lane < 8) *(bf16x8*)(&ql[lane * 8]) = *(const bf16x8*)(qrow + lane * 8);
    wave_lds_fence();

    // diag key j=i (always valid): lane = dim, full-wave reduce
    float sd = bf2f((short)ql[lane]) * bf2f((short)kbase[(size_t)iv * NHD + lane]);
    for (int off = 1; off < 64; off <<= 1) sd += __shfl_xor(sd, off, 64);
    sd *= 0.125f;

    // 32 candidate keys, 2 lanes per key (half = 32 dims each)
    const int c = lane >> 1, half = lane & 1;
    int j, valid;
    if (c < 16) {
      j = i - NHWIN + c;  // window j = i-16 .. i-1
      valid = (j >= 0);
    } else {
      const int* rr = rand_idx + ((size_t)b * NS + iv) * NRC;
      const int cr = c - 16;
      j = rr[cr];
      valid = (j <= i - NHWIN - 1);  // causal AND strictly below window
      for (int cp = 0; cp < cr; cp++) valid &= (rr[cp] != j);  // first occurrence wins
    }
    const int jr = valid ? j : 0;
    float s = 0.f;
    {
      const u16* krow = kbase + (size_t)jr * NHD + half * 32;
      for (int c8 = 0; c8 < 4; c8++) {
        bf16x8 kv = *(const bf16x8*)(krow + c8 * 8);
        bf16x8 qv = *(const bf16x8*)(&ql[half * 32 + c8 * 8]);
        for (int e = 0; e < 8; e++) s += bf2f(qv[e]) * bf2f(kv[e]);
      }
    }
    s += __shfl_xor(s, 1, 64);  // combine halves
    s = valid ? s * 0.125f : -INFINITY;

    float smax = s;
    for (int off = 1; off < 64; off <<= 1) smax = fmaxf(smax, __shfl_xor(smax, off, 64));
    smax = fmaxf(smax, sd);
    float p = valid ? __expf(s - smax) : 0.f;
    float pd = __expf(sd - smax);
    float pm = (half == 0) ? p : 0.f;
    for (int off = 1; off < 64; off <<= 1) pm += __shfl_xor(pm, off, 64);
    const float lsum = pm + pd;

    if (half == 0) {
      pl[c] = p;
      jl[c] = jr;
    }
    if (lane == 0) {
      pl[32] = pd;
      jl[32] = iv;
    }
    wave_lds_fence();

    // PV: lane = output dim; key index wave-uniform -> SGPR base via readfirstlane
    float o = 0.f;
    for (int jj = 0; jj < 33; jj++) {
      const int jk = __builtin_amdgcn_readfirstlane(jl[jj]);
      const float pj = pl[jj];
      o += pj * bf2f((short)vbase[(size_t)jk * NHD + lane]);
    }
    if (i >= 0)
      attnb[((size_t)(b * NS + i) * NH + h) * NHD + lane] = f2bf(o / lsum);
  } else {
    // ================= important rows: gathered, pure causal, 8-way key-split, 64-key tiles ======
    u16* Pl = (u16*)smem + wave * 16 * PSTR;  // per-wave 2304 B
    const int gw = (blockIdx.x - NSBLK) * 4 + wave;
    const int qt = gw % (NILIST / 16);
    const int chunk = (gw / (NILIST / 16)) % NCHUNK;
    const int bh = gw / ((NILIST / 16) * NCHUNK);
    const int b = bh >> 3, h = bh & 7;
    const int quad = lane >> 4, col = lane & 15;

    const int* il = ilist + b * NILIST;
    const u16* qptr = qb + (size_t)(b * NH + h) * NS * NHD;
    const u16* kptr = kb + (size_t)(b * NH + h) * NS * NHD;
    const u16* vptr = vtb + (size_t)(b * NH + h) * NHD * NS;

    const int iq = il[qt * 16 + col];
    const int qrow = (iq < 0) ? 0 : iq;
    bf16x8 qf0 = *(const bf16x8*)(qptr + qrow * NHD + quad * 8);
    bf16x8 qf1 = *(const bf16x8*)(qptr + qrow * NHD + 32 + quad * 8);

    float m_r[4], l_r[4];
    f32x4 of[4];
    int irow[4];
    for (int r = 0; r < 4; r++) {
      m_r[r] = -INFINITY;
      l_r[r] = 0.f;
      irow[r] = il[qt * 16 + quad * 4 + r];  // -1 for padding rows
    }
    for (int n = 0; n < 4; n++) of[n] = zf;

    const int max_i = il[(qt * 16 + 15 > NKTOP - 1) ? (NKTOP - 1) : (qt * 16 + 15)];
    const int ntiles = (max_i >> 6) + 1;  // 64-key tiles
    for (int t = chunk; t < ntiles; t += NCHUNK) {
      const int j0 = t * 64;
      f32x4 cg[4];
      for (int g = 0; g < 4; g++) {
        const int jb = j0 + g * 16;
        bf16x8 k0f = *(const bf16x8*)(kptr + (jb + col) * NHD + quad * 8);
        bf16x8 k1f = *(const bf16x8*)(kptr + (jb + col) * NHD + 32 + quad * 8);
        f32x4 cc = zf;
        cc = __builtin_amdgcn_mfma_f32_16x16x32_bf16(qf0, k0f, cc, 0, 0, 0);
        cc = __builtin_amdgcn_mfma_f32_16x16x32_bf16(qf1, k1f, cc, 0, 0, 0);
        cg[g] = cc;
      }
      float ps[4][4], alpha[4];
      for (int r = 0; r < 4; r++) {
        const int i = irow[r];
        float s[4];
        float vmax = -INFINITY;
        for (int g = 0; g < 4; g++) {
          s[g] = (j0 + g * 16 + col <= i) ? cg[g][r] * 0.125f : -INFINITY;
          vmax = fmaxf(vmax, s[g]);
        }
        for (int off = 1; off < 16; off <<= 1) vmax = fmaxf(vmax, __shfl_xor(vmax, off, 64));
        float newm = fmaxf(m_r[r], vmax);
        bool dead = (newm == -INFINITY);
        float a = dead ? 1.f : __expf(m_r[r] - newm);
        float psum = 0.f;
        for (int g = 0; g < 4; g++) {
          float pp = dead ? 0.f : __expf(s[g] - newm);
          ps[r][g] = pp;
          psum += pp;
        }
        for (int off = 1; off < 16; off <<= 1) psum += __shfl_xor(psum, off, 64);
        m_r[r] = newm;
        l_r[r] = l_r[r] * a + psum;
        alpha[r] = a;
      }
      for (int n = 0; n < 4; n++)
        for (int r = 0; r < 4; r++) of[n][r] *= alpha[r];
      // P: C-layout -> per-wave LDS -> A-layout (wave-synchronous round trip)
      for (int r = 0; r < 4; r++)
        for (int g = 0; g < 4; g++)
          Pl[(quad * 4 + r) * PSTR + g * 16 + col] = f2bf(ps[r][g]);
      wave_lds_fence();
      bf16x8 pf0 = *(const bf16x8*)(&Pl[col * PSTR + quad * 8]);
      bf16x8 pf1 = *(const bf16x8*)(&Pl[col * PSTR + 32 + quad * 8]);
      wave_lds_fence();  // reads done before next iteration overwrites
      for (int vn = 0; vn < 4; vn++) {
        bf16x8 vf0 = *(const bf16x8*)(vptr + (size_t)(vn * 16 + col) * NS + j0 + quad * 8);
        bf16x8 vf1 = *(const bf16x8*)(vptr + (size_t)(vn * 16 + col) * NS + j0 + 32 + quad * 8);
        of[vn] = __builtin_amdgcn_mfma_f32_16x16x32_bf16(pf0, vf0, of[vn], 0, 0, 0);
        of[vn] = __builtin_amdgcn_mfma_f32_16x16x32_bf16(pf1, vf1, of[vn], 0, 0, 0);
      }
    }
    float* pr = pbuf + ((size_t)(bh * NCHUNK + chunk) * NILIST + qt * 16) * 66;
    for (int r = 0; r < 4; r++) {
      const int row = quad * 4 + r;
      if (col == 0) {
        pr[row * 66 + 0] = m_r[r];
        pr[row * 66 + 1] = l_r[r];
      }
      for (int vn = 0; vn < 4; vn++)
        pr[row * 66 + 2 + vn * 16 + col] = of[vn][r];
    }
  }
}

// -------- merge important-row partials --------
__global__ __launch_bounds__(64) void csa_merge(const float* __restrict__ pbuf, const int* __restrict__ ilist,
                                                u16* __restrict__ attnb) {
  const int kp = blockIdx.x, h = blockIdx.y, b = blockIdx.z;
  const int lane = threadIdx.x;  // = d
  const int z = b * NH + h;
  float mc[NCHUNK], lc[NCHUNK], mstar = -INFINITY;
  for (int c = 0; c < NCHUNK; c++) {
    const float* base = pbuf + ((size_t)(z * NCHUNK + c) * NILIST + kp) * 66;
    mc[c] = base[0];
    lc[c] = base[1];
    mstar = fmaxf(mstar, mc[c]);
  }
  float lsum = 0.f, osum = 0.f;
  for (int c = 0; c < NCHUNK; c++) {
    const float* base = pbuf + ((size_t)(z * NCHUNK + c) * NILIST + kp) * 66;
    float w = (mc[c] == -INFINITY) ? 0.f : __expf(mc[c] - mstar);
    lsum += w * lc[c];
    osum += w * base[2 + lane];
  }
  const int i = ilist[b * NILIST + kp];
  attnb[((size_t)(b * NS + i) * NH + h) * NHD + lane] = f2bf(osum / lsum);
}

extern "C" void kernel_launch(void* const* d_in, const int* in_sizes, int n_in,
                              void* d_out, int out_size, void* d_ws, size_t ws_size,
                              hipStream_t stream) {
  const float* x = (const float*)d_in[0];
  const float* bq = (const float*)d_in[2];
  const float* bk = (const float*)d_in[4];
  const float* bv = (const float*)d_in[6];
  const float* bo = (const float*)d_in[8];
  const float* Ws1 = (const float*)d_in[9];
  const float* bs1 = (const float*)d_in[10];
  const float* Ws2 = (const float*)d_in[11];
  const int* rand_idx = (const int*)d_in[13];
  float* out = (float*)d_out;

  // workspace layout (~33 MB)
  char* p = (char*)d_ws;
  u16* wt = (u16*)p;         p += (size_t)4 * ND * ND * 2;         // 2 MB  [Wq^T;Wk^T;Wv^T;Wo^T] bf16
  u16* qbuf = (u16*)p;       p += (size_t)NB * NH * NS * NHD * 2;  // 4 MB [B,H,S,HD]
  u16* kbuf = (u16*)p;       p += (size_t)NB * NH * NS * NHD * 2;  // 4 MB
  u16* vtbuf = (u16*)p;      p += (size_t)NB * NH * NHD * NS * 2;  // 4 MB [B,H,HD,S]
  u16* vbuf = (u16*)p;       p += (size_t)NB * NH * NS * NHD * 2;  // 4 MB [B,H,S,HD]
  u16* attnb = (u16*)p;      p += (size_t)NB * NS * ND * 2;        // 4 MB [B,S,H,HD]
  float* part = (float*)p;   p += (size_t)NB * NS * 4 * 4;         // 64 KB logit partials
  int* rowimp = (int*)p;     p += (size_t)NB * NS * 4;
  int* ilist = (int*)p;      p += (size_t)NB * NILIST * 4;
  int* nlist = (int*)p;      p += (size_t)NB * NSPAD * 4;
  float* pbuf = (float*)p;   // 10.8 MB partials

  // scorer + weight transpose (one launch, scorer first - it gates the rank chain)
  csa_prep<<<dim3(768), 256, 0, stream>>>((const float*)d_in[1], (const float*)d_in[3],
                                          (const float*)d_in[5], (const float*)d_in[7], wt,
                                          x, Ws1, bs1, Ws2, part);
  csa_rank<<<dim3(NS / 8, NB), 256, 0, stream>>>(part, rowimp);
  csa_ilist<<<dim3(NB), 256, 0, stream>>>(rowimp, ilist, nlist);

  // fused QKV projection (reads fp32 x directly)
  csa_gemm_qkv<<<dim3(32, 24), 256, 0, stream>>>(x, wt, bq, bk, bv, qbuf, kbuf, vtbuf, vbuf);

  // fused attention: sparse (VALU-bound) + important (MFMA-bound) co-scheduled in one launch
  csa_attn<<<dim3(NSBLK + NIBLK), 256, 0, stream>>>(qbuf, kbuf, vbuf, vtbuf, ilist, nlist,
                                                    rand_idx, pbuf, attnb);
  csa_merge<<<dim3(NKTOP, NH, NB), 64, 0, stream>>>(pbuf, ilist, attnb);

  // output projection
  csa_gemm_out<<<dim3(64, 8), 256, 0, stream>>>(attnb, wt + 3 * (size_t)ND * ND, bo, out);
}

// Round 8
// 216.031 us; speedup vs baseline: 1.0079x; 1.0079x over previous
//
#include <hip/hip_runtime.h>
#include <math.h>

typedef unsigned short u16;
typedef unsigned int u32;
typedef unsigned long long u64;
typedef short bf16x8 __attribute__((ext_vector_type(8)));
typedef float f32x4 __attribute__((ext_vector_type(4)));

constexpr int NB = 2, NS = 2048, ND = 512, NH = 8, NHD = 64;
constexpr int NKTOP = 307, NHWIN = 16, NRC = 16;
constexpr int NILIST = 320;        // 20 tiles of 16 (padded with -1)
constexpr int NSPAR = NS - NKTOP;  // 1741 non-important rows (exact: rank is a permutation)
constexpr int NSPAD = 1744;        // padded to multiple of 4
constexpr int NCHUNK = 8;          // key-split factor for important-row attention
constexpr int LDSK64 = 72;         // 144B row stride for 64-k tiles
constexpr int PSTR = 72;           // P-tile row stride (16 rows x 64 keys)

__device__ __forceinline__ u16 f2bf(float f) {
  u32 u = __builtin_bit_cast(u32, f);
  u32 r = (u + 0x7FFFu + ((u >> 16) & 1u)) >> 16;  // RNE
  return (u16)r;
}
__device__ __forceinline__ float bf2f(short v) {
  return __builtin_bit_cast(float, (u32)(u16)v << 16);
}

// -------- fused prep: scorer (0..255) + weight transpose (256..767) + x cvt (768..1791) --------
// scorer: part[row][ny] = relu(x@Ws1+bs1).Ws2 over 64-col slice (fp32).
// sigmoid and bs2 are strictly monotone / constant -> ranking on raw logits is identical.
__global__ __launch_bounds__(256) void csa_prep(const float* __restrict__ W0, const float* __restrict__ W1,
                                                const float* __restrict__ W2, const float* __restrict__ W3,
                                                u16* __restrict__ wt, const float* __restrict__ x,
                                                u16* __restrict__ xb, const float* __restrict__ Ws1,
                                                const float* __restrict__ bs1, const float* __restrict__ Ws2,
                                                float* __restrict__ part) {
  __shared__ float sh[2 * 32 * 68];  // 17.4 KB: scorer As+Bs; cvt tile (64x33) fits too
  const int tid = threadIdx.x;
  if (blockIdx.x < 256) {
    // ---- scorer 64x64 tile ----
    const int m0 = (blockIdx.x & 63) * 64, n0 = (blockIdx.x >> 6) * 64;
    float(*As)[68] = (float(*)[68])sh;
    float(*Bs)[68] = (float(*)[68])(sh + 32 * 68);
    const int ty = tid >> 4, tx = tid & 15;
    float acc[4][4] = {};
    const int arow = tid & 63, aks = (tid >> 6) * 8;
    const int bk = tid >> 3, bc = (tid & 7) * 8;
    for (int k0 = 0; k0 < ND; k0 += 32) {
      __syncthreads();
      {
        float4 a0 = *(const float4*)(&x[(size_t)(m0 + arow) * ND + k0 + aks]);
        float4 a1 = *(const float4*)(&x[(size_t)(m0 + arow) * ND + k0 + aks + 4]);
        As[aks + 0][arow] = a0.x; As[aks + 1][arow] = a0.y;
        As[aks + 2][arow] = a0.z; As[aks + 3][arow] = a0.w;
        As[aks + 4][arow] = a1.x; As[aks + 5][arow] = a1.y;
        As[aks + 6][arow] = a1.z; As[aks + 7][arow] = a1.w;
      }
      *(float4*)(&Bs[bk][bc]) = *(const float4*)(&Ws1[(size_t)(k0 + bk) * 256 + n0 + bc]);
      *(float4*)(&Bs[bk][bc + 4]) = *(const float4*)(&Ws1[(size_t)(k0 + bk) * 256 + n0 + bc + 4]);
      __syncthreads();
      for (int k = 0; k < 32; k++) {
        float4 av = *(const float4*)(&As[k][ty * 4]);
        float4 bv = *(const float4*)(&Bs[k][tx * 4]);
        float aa[4] = {av.x, av.y, av.z, av.w};
        float bb[4] = {bv.x, bv.y, bv.z, bv.w};
        for (int i = 0; i < 4; i++)
          for (int j = 0; j < 4; j++)
            acc[i][j] += aa[i] * bb[j];
      }
    }
    float4 w2 = *(const float4*)(&Ws2[n0 + tx * 4]);
    float4 b1 = *(const float4*)(&bs1[n0 + tx * 4]);
    for (int i = 0; i < 4; i++) {
      float p = fmaxf(acc[i][0] + b1.x, 0.f) * w2.x + fmaxf(acc[i][1] + b1.y, 0.f) * w2.y +
                fmaxf(acc[i][2] + b1.z, 0.f) * w2.z + fmaxf(acc[i][3] + b1.w, 0.f) * w2.w;
      for (int off = 1; off < 16; off <<= 1) p += __shfl_xor(p, off, 64);
      if (tx == 0) part[(size_t)(m0 + ty * 4 + i) * 4 + (blockIdx.x >> 6)] = p;
    }
  } else if (blockIdx.x < 768) {
    // ---- weight transpose: W[K][N] fp32 -> Wt[N][K] bf16, 128B packed writes ----
    const int cb = blockIdx.x - 256;
    const int w = cb >> 7;
    const int kb = ((cb & 127) >> 4) * 64;
    const int nb = (cb & 15) * 32;
    const float* src = (w == 0) ? W0 : (w == 1) ? W1 : (w == 2) ? W2 : W3;
    float(*tile)[33] = (float(*)[33])sh;
    int tx = tid & 31, ty = tid >> 5;
    for (int i = ty; i < 64; i += 8) tile[i][tx] = src[(size_t)(kb + i) * ND + nb + tx];
    __syncthreads();
    u16* dst = wt + (size_t)w * ND * ND;
    for (int n = ty; n < 32; n += 8) {
      u32 pk = (u32)f2bf(tile[2 * tx][n]) | ((u32)f2bf(tile[2 * tx + 1][n]) << 16);
      *(u32*)(&dst[(size_t)(nb + n) * ND + kb + 2 * tx]) = pk;
    }
  } else {
    // ---- x fp32 -> bf16, one-time (removes 24x redundant conversion in qkv staging) ----
    const int i = ((blockIdx.x - 768) * 256 + tid) * 8;
    float4 v0 = *(const float4*)(x + i);
    float4 v1 = *(const float4*)(x + i + 4);
    u32 o0 = (u32)f2bf(v0.x) | ((u32)f2bf(v0.y) << 16);
    u32 o1 = (u32)f2bf(v0.z) | ((u32)f2bf(v0.w) << 16);
    u32 o2 = (u32)f2bf(v1.x) | ((u32)f2bf(v1.y) << 16);
    u32 o3 = (u32)f2bf(v1.z) | ((u32)f2bf(v1.w) << 16);
    uint4 o = {o0, o1, o2, o3};
    *(uint4*)(xb + i) = o;
  }
}

// -------- exact top-k on logits (lax.top_k tie semantics: lower index wins), wave per 2 rows --------
__global__ __launch_bounds__(256) void csa_rank(const float* __restrict__ part, int* __restrict__ rowimp) {
  __shared__ float vals[NS];
  const int b = blockIdx.y;
  {
    int t8 = threadIdx.x * 8;
    for (int e = 0; e < 8; e++) {
      float4 pp = *(const float4*)(&part[(size_t)(b * NS + t8 + e) * 4]);
      vals[t8 + e] = (pp.x + pp.y) + (pp.z + pp.w);  // fixed order -> deterministic
    }
  }
  __syncthreads();
  const int wave = threadIdx.x >> 6, lane = threadIdx.x & 63;
  const int s0 = blockIdx.x * 8 + wave * 2;  // two rows per wave
  const int s1 = s0 + 1;
  const float v0 = vals[s0], v1 = vals[s1];
  int r0 = 0, r1 = 0;
  for (int t = lane; t < NS; t += 64) {
    float u = vals[t];
    r0 += (int)((u > v0) | ((u == v0) & (t < s0)));
    r1 += (int)((u > v1) | ((u == v1) & (t < s1)));
  }
  for (int off = 1; off < 64; off <<= 1) {
    r0 += __shfl_xor(r0, off, 64);
    r1 += __shfl_xor(r1, off, 64);
  }
  if (lane == 0) {
    rowimp[b * NS + s0] = (r0 < NKTOP) ? 1 : 0;
    rowimp[b * NS + s1] = (r1 < NKTOP) ? 1 : 0;
  }
}

// -------- compact important rows (and complement) into sorted lists --------
__global__ __launch_bounds__(256) void csa_ilist(const int* __restrict__ rowimp, int* __restrict__ ilist,
                                                 int* __restrict__ nlist) {
  __shared__ int cs[256];
  int b = blockIdx.x, t = threadIdx.x;
  int flags[8], sum = 0;
  for (int k = 0; k < 8; k++) {
    flags[k] = rowimp[b * NS + t * 8 + k];
    sum += flags[k];
  }
  cs[t] = sum;
  __syncthreads();
  for (int off = 1; off < 256; off <<= 1) {
    int v = (t >= off) ? cs[t - off] : 0;
    __syncthreads();
    cs[t] += v;
    __syncthreads();
  }
  int pos = cs[t] - sum;  // important rows before t*8
  for (int k = 0; k < 8; k++) {
    int r = t * 8 + k;
    if (flags[k]) ilist[b * NILIST + pos++] = r;
    else nlist[b * NSPAD + (r - pos)] = r;  // r - pos = non-important rows before r
  }
  if (t < NILIST - NKTOP) ilist[b * NILIST + NKTOP + t] = -1;
  if (t < NSPAD - NSPAR) nlist[b * NSPAD + NSPAR + t] = -1;
}

// -------- fused QKV projection: pure bf16 MFMA, 128x64 tile, K=64 stages, N=1536 --------
__global__ __launch_bounds__(256) void csa_gemm_qkv(const u16* __restrict__ xb, const u16* __restrict__ Bt,
                                                    const float* __restrict__ bq, const float* __restrict__ bk,
                                                    const float* __restrict__ bv, u16* __restrict__ qb,
                                                    u16* __restrict__ kb, u16* __restrict__ vtb,
                                                    u16* __restrict__ vb) {
  __shared__ __attribute__((aligned(16))) u16 As[128 * LDSK64];  // 18.4 KB
  __shared__ __attribute__((aligned(16))) u16 Bs[64 * LDSK64];   // 9.2 KB
  const int tid = threadIdx.x;
  const int wave = tid >> 6, lane = tid & 63;
  const int quad = lane >> 4, col = lane & 15;
  const int m0 = blockIdx.x * 128;
  const int n0 = blockIdx.y * 64;
  const f32x4 zf = {0.f, 0.f, 0.f, 0.f};
  f32x4 acc[2][4] = {{zf, zf, zf, zf}, {zf, zf, zf, zf}};
  const int sar = tid >> 1, sak = (tid & 1) * 32;  // A: 128 rows x 64 k, 32 u16/thread
  const int sbr = tid >> 2, sbk = (tid & 3) * 16;  // B: 64 rows x 64 k, 16 u16/thread
  for (int k0 = 0; k0 < ND; k0 += 64) {
    __syncthreads();
    {
      const u16* xp = &xb[(size_t)(m0 + sar) * ND + k0 + sak];
      u16* ap = &As[sar * LDSK64 + sak];
      *(uint4*)(ap) = *(const uint4*)(xp);
      *(uint4*)(ap + 8) = *(const uint4*)(xp + 8);
      *(uint4*)(ap + 16) = *(const uint4*)(xp + 16);
      *(uint4*)(ap + 24) = *(const uint4*)(xp + 24);
    }
    *(uint4*)(&Bs[sbr * LDSK64 + sbk]) = *(const uint4*)(&Bt[(size_t)(n0 + sbr) * ND + k0 + sbk]);
    *(uint4*)(&Bs[sbr * LDSK64 + sbk + 8]) = *(const uint4*)(&Bt[(size_t)(n0 + sbr) * ND + k0 + sbk + 8]);
    __syncthreads();
    bf16x8 af[2][2];
    for (int r = 0; r < 2; r++)
      for (int hh = 0; hh < 2; hh++)
        af[r][hh] = *(const bf16x8*)(&As[(wave * 32 + r * 16 + col) * LDSK64 + hh * 32 + quad * 8]);
    for (int c = 0; c < 4; c++) {
      bf16x8 b0 = *(const bf16x8*)(&Bs[(c * 16 + col) * LDSK64 + quad * 8]);
      bf16x8 b1 = *(const bf16x8*)(&Bs[(c * 16 + col) * LDSK64 + 32 + quad * 8]);
      acc[0][c] = __builtin_amdgcn_mfma_f32_16x16x32_bf16(af[0][0], b0, acc[0][c], 0, 0, 0);
      acc[0][c] = __builtin_amdgcn_mfma_f32_16x16x32_bf16(af[0][1], b1, acc[0][c], 0, 0, 0);
      acc[1][c] = __builtin_amdgcn_mfma_f32_16x16x32_bf16(af[1][0], b0, acc[1][c], 0, 0, 0);
      acc[1][c] = __builtin_amdgcn_mfma_f32_16x16x32_bf16(af[1][1], b1, acc[1][c], 0, 0, 0);
    }
  }
  const int w = n0 >> 9;  // 0=Q 1=K 2=V (uniform per block; 64-tiles align in 512 regions)
  const float* bias = (w == 0) ? bq : (w == 1) ? bk : bv;
  for (int c = 0; c < 4; c++) {
    const int ng = n0 + c * 16 + col;
    const int nn = ng & 511, hh = nn >> 6, hd = nn & 63;
    const float bvv = bias[nn];
    for (int r = 0; r < 2; r++) {
      for (int rr = 0; rr < 4; rr++) {
        const int m = m0 + wave * 32 + r * 16 + quad * 4 + rr;
        const int bb = m >> 11, s = m & (NS - 1);
        u16 v16 = f2bf(acc[r][c][rr] + bvv);
        if (w == 0) qb[((size_t)(bb * NH + hh) * NS + s) * NHD + hd] = v16;
        else if (w == 1) kb[((size_t)(bb * NH + hh) * NS + s) * NHD + hd] = v16;
        else {
          vtb[((size_t)(bb * NH + hh) * NHD + hd) * NS + s] = v16;
          vb[((size_t)(bb * NH + hh) * NS + s) * NHD + hd] = v16;
        }
      }
    }
  }
}

// -------- output projection: bf16 MFMA 64x64 tile, K=64 stages, fp32 out --------
__global__ __launch_bounds__(256) void csa_gemm_out(const u16* __restrict__ A, const u16* __restrict__ Bt,
                                                    const float* __restrict__ bias, float* __restrict__ outp) {
  __shared__ __attribute__((aligned(16))) u16 As[64 * LDSK64];
  __shared__ __attribute__((aligned(16))) u16 Bs[64 * LDSK64];
  const int tid = threadIdx.x;
  const int wave = tid >> 6, lane = tid & 63;
  const int quad = lane >> 4, col = lane & 15;
  const int m0 = blockIdx.x * 64;
  const int n0 = blockIdx.y * 64;
  const f32x4 zf = {0.f, 0.f, 0.f, 0.f};
  f32x4 acc[4] = {zf, zf, zf, zf};
  const int sr = tid >> 2, sk = (tid & 3) * 16;  // 64 rows x 64 k, 16 u16/thread
  for (int k0 = 0; k0 < ND; k0 += 64) {
    __syncthreads();
    *(uint4*)(&As[sr * LDSK64 + sk]) = *(const uint4*)(&A[(size_t)(m0 + sr) * ND + k0 + sk]);
    *(uint4*)(&As[sr * LDSK64 + sk + 8]) = *(const uint4*)(&A[(size_t)(m0 + sr) * ND + k0 + sk + 8]);
    *(uint4*)(&Bs[sr * LDSK64 + sk]) = *(const uint4*)(&Bt[(size_t)(n0 + sr) * ND + k0 + sk]);
    *(uint4*)(&Bs[sr * LDSK64 + sk + 8]) = *(const uint4*)(&Bt[(size_t)(n0 + sr) * ND + k0 + sk + 8]);
    __syncthreads();
    bf16x8 af0 = *(const bf16x8*)(&As[(wave * 16 + col) * LDSK64 + quad * 8]);
    bf16x8 af1 = *(const bf16x8*)(&As[(wave * 16 + col) * LDSK64 + 32 + quad * 8]);
    for (int nt = 0; nt < 4; nt++) {
      bf16x8 bf0 = *(const bf16x8*)(&Bs[(nt * 16 + col) * LDSK64 + quad * 8]);
      bf16x8 bf1 = *(const bf16x8*)(&Bs[(nt * 16 + col) * LDSK64 + 32 + quad * 8]);
      acc[nt] = __builtin_amdgcn_mfma_f32_16x16x32_bf16(af0, bf0, acc[nt], 0, 0, 0);
      acc[nt] = __builtin_amdgcn_mfma_f32_16x16x32_bf16(af1, bf1, acc[nt], 0, 0, 0);
    }
  }
  for (int nt = 0; nt < 4; nt++) {
    const int n = n0 + nt * 16 + col;
    const float bvv = bias[n];
    for (int r = 0; r < 4; r++) {
      const int m = m0 + wave * 16 + quad * 4 + r;
      outp[(size_t)m * ND + n] = acc[nt][r] + bvv;
    }
  }
}

// -------- important-row attention: gathered rows, pure causal, 8-way key-split, 64-key tiles --------
// partials pbuf[((bh*8+chunk)*NILIST + row)*66] = {m, l, o[64] unnormalized}
__global__ __launch_bounds__(64) void csa_attn_imp(const u16* __restrict__ qb, const u16* __restrict__ kb,
                                                   const u16* __restrict__ vtb, const int* __restrict__ ilist,
                                                   float* __restrict__ pbuf) {
  const int lane = threadIdx.x;
  const int quad = lane >> 4, col = lane & 15;
  const int qt = blockIdx.x;     // 0..19
  const int chunk = blockIdx.y;  // 0..7
  const int bh = blockIdx.z;     // 0..15
  const int b = bh >> 3, h = bh & 7;

  const int* il = ilist + b * NILIST;
  const u16* qptr = qb + (size_t)(b * NH + h) * NS * NHD;
  const u16* kptr = kb + (size_t)(b * NH + h) * NS * NHD;
  const u16* vptr = vtb + (size_t)(b * NH + h) * NHD * NS;

  const int iq = il[qt * 16 + col];
  const int qrow = (iq < 0) ? 0 : iq;
  bf16x8 qf0 = *(const bf16x8*)(qptr + qrow * NHD + quad * 8);
  bf16x8 qf1 = *(const bf16x8*)(qptr + qrow * NHD + 32 + quad * 8);

  const f32x4 zf = {0.f, 0.f, 0.f, 0.f};
  float m_r[4], l_r[4];
  f32x4 of[4];
  int irow[4];
  for (int r = 0; r < 4; r++) {
    m_r[r] = -INFINITY;
    l_r[r] = 0.f;
    irow[r] = il[qt * 16 + quad * 4 + r];  // -1 for padding rows
  }
  for (int n = 0; n < 4; n++) of[n] = zf;

  __shared__ __attribute__((aligned(16))) u16 Pl[16 * PSTR];

  const int max_i = il[(qt * 16 + 15 > NKTOP - 1) ? (NKTOP - 1) : (qt * 16 + 15)];
  const int ntiles = (max_i >> 6) + 1;  // 64-key tiles
  for (int t = chunk; t < ntiles; t += NCHUNK) {
    const int j0 = t * 64;
    f32x4 cg[4];
    for (int g = 0; g < 4; g++) {
      const int jb = j0 + g * 16;
      bf16x8 k0f = *(const bf16x8*)(kptr + (jb + col) * NHD + quad * 8);
      bf16x8 k1f = *(const bf16x8*)(kptr + (jb + col) * NHD + 32 + quad * 8);
      f32x4 c = zf;
      c = __builtin_amdgcn_mfma_f32_16x16x32_bf16(qf0, k0f, c, 0, 0, 0);
      c = __builtin_amdgcn_mfma_f32_16x16x32_bf16(qf1, k1f, c, 0, 0, 0);
      cg[g] = c;
    }
    float ps[4][4], alpha[4];
    for (int r = 0; r < 4; r++) {
      const int i = irow[r];
      float s[4];
      float vmax = -INFINITY;
      for (int g = 0; g < 4; g++) {
        s[g] = (j0 + g * 16 + col <= i) ? cg[g][r] * 0.125f : -INFINITY;
        vmax = fmaxf(vmax, s[g]);
      }
      for (int off = 1; off < 16; off <<= 1) vmax = fmaxf(vmax, __shfl_xor(vmax, off, 64));
      float newm = fmaxf(m_r[r], vmax);
      bool dead = (newm == -INFINITY);
      float a = dead ? 1.f : __expf(m_r[r] - newm);
      float psum = 0.f;
      for (int g = 0; g < 4; g++) {
        float p = dead ? 0.f : __expf(s[g] - newm);
        ps[r][g] = p;
        psum += p;
      }
      for (int off = 1; off < 16; off <<= 1) psum += __shfl_xor(psum, off, 64);
      m_r[r] = newm;
      l_r[r] = l_r[r] * a + psum;
      alpha[r] = a;
    }
    for (int n = 0; n < 4; n++)
      for (int r = 0; r < 4; r++) of[n][r] *= alpha[r];
    __syncthreads();
    for (int r = 0; r < 4; r++)
      for (int g = 0; g < 4; g++)
        Pl[(quad * 4 + r) * PSTR + g * 16 + col] = f2bf(ps[r][g]);
    __syncthreads();
    bf16x8 pf0 = *(const bf16x8*)(&Pl[col * PSTR + quad * 8]);
    bf16x8 pf1 = *(const bf16x8*)(&Pl[col * PSTR + 32 + quad * 8]);
    for (int vn = 0; vn < 4; vn++) {
      bf16x8 vf0 = *(const bf16x8*)(vptr + (size_t)(vn * 16 + col) * NS + j0 + quad * 8);
      bf16x8 vf1 = *(const bf16x8*)(vptr + (size_t)(vn * 16 + col) * NS + j0 + 32 + quad * 8);
      of[vn] = __builtin_amdgcn_mfma_f32_16x16x32_bf16(pf0, vf0, of[vn], 0, 0, 0);
      of[vn] = __builtin_amdgcn_mfma_f32_16x16x32_bf16(pf1, vf1, of[vn], 0, 0, 0);
    }
  }
  float* pr = pbuf + ((size_t)(bh * NCHUNK + chunk) * NILIST + qt * 16) * 66;
  for (int r = 0; r < 4; r++) {
    const int row = quad * 4 + r;
    if (col == 0) {
      pr[row * 66 + 0] = m_r[r];
      pr[row * 66 + 1] = l_r[r];
    }
    for (int vn = 0; vn < 4; vn++)
      pr[row * 66 + 2 + vn * 16 + col] = of[vn][r];
  }
}

// -------- merge important-row partials --------
__global__ __launch_bounds__(64) void csa_merge(const float* __restrict__ pbuf, const int* __restrict__ ilist,
                                                u16* __restrict__ attnb) {
  const int kp = blockIdx.x, h = blockIdx.y, b = blockIdx.z;
  const int lane = threadIdx.x;  // = d
  const int z = b * NH + h;
  float mc[NCHUNK], lc[NCHUNK], mstar = -INFINITY;
  for (int c = 0; c < NCHUNK; c++) {
    const float* base = pbuf + ((size_t)(z * NCHUNK + c) * NILIST + kp) * 66;
    mc[c] = base[0];
    lc[c] = base[1];
    mstar = fmaxf(mstar, mc[c]);
  }
  float lsum = 0.f, osum = 0.f;
  for (int c = 0; c < NCHUNK; c++) {
    const float* base = pbuf + ((size_t)(z * NCHUNK + c) * NILIST + kp) * 66;
    float w = (mc[c] == -INFINITY) ? 0.f : __expf(mc[c] - mstar);
    lsum += w * lc[c];
    osum += w * base[2 + lane];
  }
  const int i = ilist[b * NILIST + kp];
  attnb[((size_t)(b * NS + i) * NH + h) * NHD + lane] = f2bf(osum / lsum);
}

// -------- sparse-row attention: non-important rows only, zero LDS, readlane PV broadcast --------
__global__ __launch_bounds__(256) void csa_attn_sparse(const u16* __restrict__ qb, const u16* __restrict__ kb,
                                                       const u16* __restrict__ vb, const int* __restrict__ nlist,
                                                       const int* __restrict__ rand_idx, u16* __restrict__ attnb) {
  const int wave = threadIdx.x >> 6, lane = threadIdx.x & 63;
  const int slot = blockIdx.x * 4 + wave;
  const int h = blockIdx.y, b = blockIdx.z;
  const int i = nlist[b * NSPAD + slot];  // -1 for the 3 pad slots
  const int iv = (i < 0) ? 0 : i;

  const u16* qrow = qb + ((size_t)(b * NH + h) * NS + iv) * NHD;
  const u16* kbase = kb + (size_t)(b * NH + h) * NS * NHD;
  const u16* vbase = vb + (size_t)(b * NH + h) * NS * NHD;

  // --- diagonal key j=i (always valid): lane = dim, full-wave reduce ---
  float sd = bf2f((short)qrow[lane]) * bf2f((short)kbase[(size_t)iv * NHD + lane]);
  for (int off = 1; off < 64; off <<= 1) sd += __shfl_xor(sd, off, 64);
  sd *= 0.125f;

  // --- 32 candidate keys, 2 lanes per key (half = 32 dims each, q chunk in registers) ---
  const int c = lane >> 1, half = lane & 1;
  int j, valid;
  if (c < 16) {
    j = i - NHWIN + c;  // window j = i-16 .. i-1
    valid = (j >= 0);
  } else {
    const int* rr = rand_idx + ((size_t)b * NS + iv) * NRC;
    const int cr = c - 16;
    j = rr[cr];
    valid = (j <= i - NHWIN - 1);  // causal AND strictly below window
    for (int cp = 0; cp < cr; cp++) valid &= (rr[cp] != j);  // first occurrence wins
  }
  const int jr = valid ? j : 0;
  float s = 0.f;
  {
    const u16* krow = kbase + (size_t)jr * NHD + half * 32;
    const u16* qh = qrow + half * 32;
    for (int c8 = 0; c8 < 4; c8++) {
      bf16x8 kv = *(const bf16x8*)(krow + c8 * 8);
      bf16x8 qv = *(const bf16x8*)(qh + c8 * 8);
      for (int e = 0; e < 8; e++) s += bf2f(qv[e]) * bf2f(kv[e]);
    }
  }
  s += __shfl_xor(s, 1, 64);  // combine halves; both lanes of pair hold full dot
  s = valid ? s * 0.125f : -INFINITY;

  // --- softmax over {32 candidates} U {diag} ---
  float smax = s;
  for (int off = 1; off < 64; off <<= 1) smax = fmaxf(smax, __shfl_xor(smax, off, 64));
  smax = fmaxf(smax, sd);
  float p = valid ? __expf(s - smax) : 0.f;
  float pd = __expf(sd - smax);
  float pm = (half == 0) ? p : 0.f;
  for (int off = 1; off < 64; off <<= 1) pm += __shfl_xor(pm, off, 64);
  const float lsum = pm + pd;

  // --- PV: lane = output dim; p/j broadcast via compile-time-lane shfl (v_readlane) ---
  float o = pd * bf2f((short)vbase[(size_t)iv * NHD + lane]);
#pragma unroll
  for (int jj = 0; jj < 32; jj++) {
    const float pj = __shfl(p, 2 * jj, 64);
    const int jk = __shfl(jr, 2 * jj, 64);
    o += pj * bf2f((short)vbase[(size_t)jk * NHD + lane]);
  }
  if (i >= 0)
    attnb[((size_t)(b * NS + i) * NH + h) * NHD + lane] = f2bf(o / lsum);
}

extern "C" void kernel_launch(void* const* d_in, const int* in_sizes, int n_in,
                              void* d_out, int out_size, void* d_ws, size_t ws_size,
                              hipStream_t stream) {
  const float* x = (const float*)d_in[0];
  const float* bq = (const float*)d_in[2];
  const float* bk = (const float*)d_in[4];
  const float* bv = (const float*)d_in[6];
  const float* bo = (const float*)d_in[8];
  const float* Ws1 = (const float*)d_in[9];
  const float* bs1 = (const float*)d_in[10];
  const float* Ws2 = (const float*)d_in[11];
  const int* rand_idx = (const int*)d_in[13];
  float* out = (float*)d_out;

  // workspace layout (~37 MB)
  char* p = (char*)d_ws;
  u16* wt = (u16*)p;         p += (size_t)4 * ND * ND * 2;         // 2 MB  [Wq^T;Wk^T;Wv^T;Wo^T] bf16
  u16* xb = (u16*)p;         p += (size_t)NB * NS * ND * 2;        // 4 MB x bf16 [4096,512]
  u16* qbuf = (u16*)p;       p += (size_t)NB * NH * NS * NHD * 2;  // 4 MB [B,H,S,HD]
  u16* kbuf = (u16*)p;       p += (size_t)NB * NH * NS * NHD * 2;  // 4 MB
  u16* vtbuf = (u16*)p;      p += (size_t)NB * NH * NHD * NS * 2;  // 4 MB [B,H,HD,S]
  u16* vbuf = (u16*)p;       p += (size_t)NB * NH * NS * NHD * 2;  // 4 MB [B,H,S,HD]
  u16* attnb = (u16*)p;      p += (size_t)NB * NS * ND * 2;        // 4 MB [B,S,H,HD]
  float* part = (float*)p;   p += (size_t)NB * NS * 4 * 4;         // 64 KB logit partials
  int* rowimp = (int*)p;     p += (size_t)NB * NS * 4;
  int* ilist = (int*)p;      p += (size_t)NB * NILIST * 4;
  int* nlist = (int*)p;      p += (size_t)NB * NSPAD * 4;
  float* pbuf = (float*)p;   // 10.8 MB partials

  // scorer + weight transpose + x conversion (one launch; scorer first - it gates the rank chain)
  csa_prep<<<dim3(1792), 256, 0, stream>>>((const float*)d_in[1], (const float*)d_in[3],
                                           (const float*)d_in[5], (const float*)d_in[7], wt,
                                           x, xb, Ws1, bs1, Ws2, part);
  csa_rank<<<dim3(NS / 8, NB), 256, 0, stream>>>(part, rowimp);
  csa_ilist<<<dim3(NB), 256, 0, stream>>>(rowimp, ilist, nlist);

  // fused QKV projection (pure bf16 GEMM)
  csa_gemm_qkv<<<dim3(32, 24), 256, 0, stream>>>(xb, wt, bq, bk, bv, qbuf, kbuf, vtbuf, vbuf);

  // attention: important rows (MFMA, 8-way split-K, 64-key tiles) + sparse rows (per-wave)
  csa_attn_imp<<<dim3(NILIST / 16, NCHUNK, NB * NH), 64, 0, stream>>>(qbuf, kbuf, vtbuf, ilist, pbuf);
  csa_attn_sparse<<<dim3(NSPAD / 4, NH, NB), 256, 0, stream>>>(qbuf, kbuf, vbuf, nlist, rand_idx, attnb);
  csa_merge<<<dim3(NKTOP, NH, NB), 64, 0, stream>>>(pbuf, ilist, attnb);

  // output projection
  csa_gemm_out<<<dim3(64, 8), 256, 0, stream>>>(attnb, wt + 3 * (size_t)ND * ND, bo, out);
}

// Round 9
// 200.024 us; speedup vs baseline: 1.0885x; 1.0800x over previous
//
#include <hip/hip_runtime.h>
#include <math.h>

typedef unsigned short u16;
typedef unsigned int u32;
typedef unsigned long long u64;
typedef short bf16x8 __attribute__((ext_vector_type(8)));
typedef float f32x4 __attribute__((ext_vector_type(4)));

constexpr int NB = 2, NS = 2048, ND = 512, NH = 8, NHD = 64;
constexpr int NKTOP = 307, NHWIN = 16, NRC = 16;
constexpr int NILIST = 320;        // 20 tiles of 16 (padded with -1)
constexpr int NSPAR = NS - NKTOP;  // 1741 non-important rows (exact: rank is a permutation)
constexpr int NSPAD = 1744;        // padded to multiple of 4
constexpr int NCHUNK = 8;          // key-split factor for important-row attention
constexpr int LDSK64 = 72;         // 144B row stride for 64-k tiles
constexpr int PSTR = 72;           // P-tile row stride (16 rows x 64 keys)

__device__ __forceinline__ u16 f2bf(float f) {
  u32 u = __builtin_bit_cast(u32, f);
  u32 r = (u + 0x7FFFu + ((u >> 16) & 1u)) >> 16;  // RNE
  return (u16)r;
}
__device__ __forceinline__ float bf2f(short v) {
  return __builtin_bit_cast(float, (u32)(u16)v << 16);
}

// -------- fused prep: scorer (0..255) + weight transpose (256..767) + x cvt (768..1791) --------
// scorer: part[row][ny] = relu(x@Ws1+bs1).Ws2 over 64-col slice (fp32).
// sigmoid and bs2 are strictly monotone / constant -> ranking on raw logits is identical.
__global__ __launch_bounds__(256) void csa_prep(const float* __restrict__ W0, const float* __restrict__ W1,
                                                const float* __restrict__ W2, const float* __restrict__ W3,
                                                u16* __restrict__ wt, const float* __restrict__ x,
                                                u16* __restrict__ xb, const float* __restrict__ Ws1,
                                                const float* __restrict__ bs1, const float* __restrict__ Ws2,
                                                float* __restrict__ part) {
  __shared__ float sh[2 * 32 * 68];  // 17.4 KB: scorer As+Bs; cvt tile (64x33) fits too
  const int tid = threadIdx.x;
  if (blockIdx.x < 256) {
    // ---- scorer 64x64 tile ----
    const int m0 = (blockIdx.x & 63) * 64, n0 = (blockIdx.x >> 6) * 64;
    float(*As)[68] = (float(*)[68])sh;
    float(*Bs)[68] = (float(*)[68])(sh + 32 * 68);
    const int ty = tid >> 4, tx = tid & 15;
    float acc[4][4] = {};
    const int arow = tid & 63, aks = (tid >> 6) * 8;
    const int bk = tid >> 3, bc = (tid & 7) * 8;
    for (int k0 = 0; k0 < ND; k0 += 32) {
      __syncthreads();
      {
        float4 a0 = *(const float4*)(&x[(size_t)(m0 + arow) * ND + k0 + aks]);
        float4 a1 = *(const float4*)(&x[(size_t)(m0 + arow) * ND + k0 + aks + 4]);
        As[aks + 0][arow] = a0.x; As[aks + 1][arow] = a0.y;
        As[aks + 2][arow] = a0.z; As[aks + 3][arow] = a0.w;
        As[aks + 4][arow] = a1.x; As[aks + 5][arow] = a1.y;
        As[aks + 6][arow] = a1.z; As[aks + 7][arow] = a1.w;
      }
      *(float4*)(&Bs[bk][bc]) = *(const float4*)(&Ws1[(size_t)(k0 + bk) * 256 + n0 + bc]);
      *(float4*)(&Bs[bk][bc + 4]) = *(const float4*)(&Ws1[(size_t)(k0 + bk) * 256 + n0 + bc + 4]);
      __syncthreads();
      for (int k = 0; k < 32; k++) {
        float4 av = *(const float4*)(&As[k][ty * 4]);
        float4 bv = *(const float4*)(&Bs[k][tx * 4]);
        float aa[4] = {av.x, av.y, av.z, av.w};
        float bb[4] = {bv.x, bv.y, bv.z, bv.w};
        for (int i = 0; i < 4; i++)
          for (int j = 0; j < 4; j++)
            acc[i][j] += aa[i] * bb[j];
      }
    }
    float4 w2 = *(const float4*)(&Ws2[n0 + tx * 4]);
    float4 b1 = *(const float4*)(&bs1[n0 + tx * 4]);
    for (int i = 0; i < 4; i++) {
      float p = fmaxf(acc[i][0] + b1.x, 0.f) * w2.x + fmaxf(acc[i][1] + b1.y, 0.f) * w2.y +
                fmaxf(acc[i][2] + b1.z, 0.f) * w2.z + fmaxf(acc[i][3] + b1.w, 0.f) * w2.w;
      for (int off = 1; off < 16; off <<= 1) p += __shfl_xor(p, off, 64);
      if (tx == 0) part[(size_t)(m0 + ty * 4 + i) * 4 + (blockIdx.x >> 6)] = p;
    }
  } else if (blockIdx.x < 768) {
    // ---- weight transpose: W[K][N] fp32 -> Wt[N][K] bf16, 128B packed writes ----
    const int cb = blockIdx.x - 256;
    const int w = cb >> 7;
    const int kb = ((cb & 127) >> 4) * 64;
    const int nb = (cb & 15) * 32;
    const float* src = (w == 0) ? W0 : (w == 1) ? W1 : (w == 2) ? W2 : W3;
    float(*tile)[33] = (float(*)[33])sh;
    int tx = tid & 31, ty = tid >> 5;
    for (int i = ty; i < 64; i += 8) tile[i][tx] = src[(size_t)(kb + i) * ND + nb + tx];
    __syncthreads();
    u16* dst = wt + (size_t)w * ND * ND;
    for (int n = ty; n < 32; n += 8) {
      u32 pk = (u32)f2bf(tile[2 * tx][n]) | ((u32)f2bf(tile[2 * tx + 1][n]) << 16);
      *(u32*)(&dst[(size_t)(nb + n) * ND + kb + 2 * tx]) = pk;
    }
  } else {
    // ---- x fp32 -> bf16, one-time (removes 24x redundant conversion in qkv staging) ----
    const int i = ((blockIdx.x - 768) * 256 + tid) * 8;
    float4 v0 = *(const float4*)(x + i);
    float4 v1 = *(const float4*)(x + i + 4);
    u32 o0 = (u32)f2bf(v0.x) | ((u32)f2bf(v0.y) << 16);
    u32 o1 = (u32)f2bf(v0.z) | ((u32)f2bf(v0.w) << 16);
    u32 o2 = (u32)f2bf(v1.x) | ((u32)f2bf(v1.y) << 16);
    u32 o3 = (u32)f2bf(v1.z) | ((u32)f2bf(v1.w) << 16);
    uint4 o = {o0, o1, o2, o3};
    *(uint4*)(xb + i) = o;
  }
}

// -------- exact top-k on logits (lax.top_k tie semantics: lower index wins), wave per 2 rows --------
__global__ __launch_bounds__(256) void csa_rank(const float* __restrict__ part, int* __restrict__ rowimp) {
  __shared__ float vals[NS];
  const int b = blockIdx.y;
  {
    int t8 = threadIdx.x * 8;
    for (int e = 0; e < 8; e++) {
      float4 pp = *(const float4*)(&part[(size_t)(b * NS + t8 + e) * 4]);
      vals[t8 + e] = (pp.x + pp.y) + (pp.z + pp.w);  // fixed order -> deterministic
    }
  }
  __syncthreads();
  const int wave = threadIdx.x >> 6, lane = threadIdx.x & 63;
  const int s0 = blockIdx.x * 8 + wave * 2;  // two rows per wave
  const int s1 = s0 + 1;
  const float v0 = vals[s0], v1 = vals[s1];
  int r0 = 0, r1 = 0;
  for (int t = lane; t < NS; t += 64) {
    float u = vals[t];
    r0 += (int)((u > v0) | ((u == v0) & (t < s0)));
    r1 += (int)((u > v1) | ((u == v1) & (t < s1)));
  }
  for (int off = 1; off < 64; off <<= 1) {
    r0 += __shfl_xor(r0, off, 64);
    r1 += __shfl_xor(r1, off, 64);
  }
  if (lane == 0) {
    rowimp[b * NS + s0] = (r0 < NKTOP) ? 1 : 0;
    rowimp[b * NS + s1] = (r1 < NKTOP) ? 1 : 0;
  }
}

// -------- compact important rows (and complement) into sorted lists --------
__global__ __launch_bounds__(256) void csa_ilist(const int* __restrict__ rowimp, int* __restrict__ ilist,
                                                 int* __restrict__ nlist) {
  __shared__ int cs[256];
  int b = blockIdx.x, t = threadIdx.x;
  int flags[8], sum = 0;
  for (int k = 0; k < 8; k++) {
    flags[k] = rowimp[b * NS + t * 8 + k];
    sum += flags[k];
  }
  cs[t] = sum;
  __syncthreads();
  for (int off = 1; off < 256; off <<= 1) {
    int v = (t >= off) ? cs[t - off] : 0;
    __syncthreads();
    cs[t] += v;
    __syncthreads();
  }
  int pos = cs[t] - sum;  // important rows before t*8
  for (int k = 0; k < 8; k++) {
    int r = t * 8 + k;
    if (flags[k]) ilist[b * NILIST + pos++] = r;
    else nlist[b * NSPAD + (r - pos)] = r;  // r - pos = non-important rows before r
  }
  if (t < NILIST - NKTOP) ilist[b * NILIST + NKTOP + t] = -1;
  if (t < NSPAD - NSPAR) nlist[b * NSPAD + NSPAR + t] = -1;
}

// -------- fused QKV projection: pure bf16 MFMA, 128x64 tile, K=64 stages, N=1536 --------
// 1-D grid, XCD swizzle: head = bid & 7 -> all writes for head h issue from XCD h (bid%8 heuristic),
// so attention's reads of head h hit that XCD's L2.
__global__ __launch_bounds__(256) void csa_gemm_qkv(const u16* __restrict__ xb, const u16* __restrict__ Bt,
                                                    const float* __restrict__ bq, const float* __restrict__ bk,
                                                    const float* __restrict__ bv, u16* __restrict__ qb,
                                                    u16* __restrict__ kb, u16* __restrict__ vtb,
                                                    u16* __restrict__ vb) {
  __shared__ __attribute__((aligned(16))) u16 As[128 * LDSK64];  // 18.4 KB
  __shared__ __attribute__((aligned(16))) u16 Bs[64 * LDSK64];   // 9.2 KB
  const int tid = threadIdx.x;
  const int wave = tid >> 6, lane = tid & 63;
  const int quad = lane >> 4, col = lane & 15;
  const int hsw = blockIdx.x & 7;          // head (XCD pin)
  const int rest = blockIdx.x >> 3;        // 0..95
  const int w = rest >> 5;                 // 0=Q 1=K 2=V
  const int m0 = (rest & 31) * 128;
  const int n0 = (w * 8 + hsw) * 64;
  const f32x4 zf = {0.f, 0.f, 0.f, 0.f};
  f32x4 acc[2][4] = {{zf, zf, zf, zf}, {zf, zf, zf, zf}};
  const int sar = tid >> 1, sak = (tid & 1) * 32;  // A: 128 rows x 64 k, 32 u16/thread
  const int sbr = tid >> 2, sbk = (tid & 3) * 16;  // B: 64 rows x 64 k, 16 u16/thread
  for (int k0 = 0; k0 < ND; k0 += 64) {
    __syncthreads();
    {
      const u16* xp = &xb[(size_t)(m0 + sar) * ND + k0 + sak];
      u16* ap = &As[sar * LDSK64 + sak];
      *(uint4*)(ap) = *(const uint4*)(xp);
      *(uint4*)(ap + 8) = *(const uint4*)(xp + 8);
      *(uint4*)(ap + 16) = *(const uint4*)(xp + 16);
      *(uint4*)(ap + 24) = *(const uint4*)(xp + 24);
    }
    *(uint4*)(&Bs[sbr * LDSK64 + sbk]) = *(const uint4*)(&Bt[(size_t)(n0 + sbr) * ND + k0 + sbk]);
    *(uint4*)(&Bs[sbr * LDSK64 + sbk + 8]) = *(const uint4*)(&Bt[(size_t)(n0 + sbr) * ND + k0 + sbk + 8]);
    __syncthreads();
    bf16x8 af[2][2];
    for (int r = 0; r < 2; r++)
      for (int hh = 0; hh < 2; hh++)
        af[r][hh] = *(const bf16x8*)(&As[(wave * 32 + r * 16 + col) * LDSK64 + hh * 32 + quad * 8]);
    for (int c = 0; c < 4; c++) {
      bf16x8 b0 = *(const bf16x8*)(&Bs[(c * 16 + col) * LDSK64 + quad * 8]);
      bf16x8 b1 = *(const bf16x8*)(&Bs[(c * 16 + col) * LDSK64 + 32 + quad * 8]);
      acc[0][c] = __builtin_amdgcn_mfma_f32_16x16x32_bf16(af[0][0], b0, acc[0][c], 0, 0, 0);
      acc[0][c] = __builtin_amdgcn_mfma_f32_16x16x32_bf16(af[0][1], b1, acc[0][c], 0, 0, 0);
      acc[1][c] = __builtin_amdgcn_mfma_f32_16x16x32_bf16(af[1][0], b0, acc[1][c], 0, 0, 0);
      acc[1][c] = __builtin_amdgcn_mfma_f32_16x16x32_bf16(af[1][1], b1, acc[1][c], 0, 0, 0);
    }
  }
  const float* bias = (w == 0) ? bq : (w == 1) ? bk : bv;
  for (int c = 0; c < 4; c++) {
    const int ng = n0 + c * 16 + col;
    const int nn = ng & 511, hh = nn >> 6, hd = nn & 63;
    const float bvv = bias[nn];
    for (int r = 0; r < 2; r++) {
      for (int rr = 0; rr < 4; rr++) {
        const int m = m0 + wave * 32 + r * 16 + quad * 4 + rr;
        const int bb = m >> 11, s = m & (NS - 1);
        u16 v16 = f2bf(acc[r][c][rr] + bvv);
        if (w == 0) qb[((size_t)(bb * NH + hh) * NS + s) * NHD + hd] = v16;
        else if (w == 1) kb[((size_t)(bb * NH + hh) * NS + s) * NHD + hd] = v16;
        else {
          vtb[((size_t)(bb * NH + hh) * NHD + hd) * NS + s] = v16;
          vb[((size_t)(bb * NH + hh) * NS + s) * NHD + hd] = v16;
        }
      }
    }
  }
}

// -------- output projection: bf16 MFMA 64x64 tile, K=64 stages, fp32 out --------
__global__ __launch_bounds__(256) void csa_gemm_out(const u16* __restrict__ A, const u16* __restrict__ Bt,
                                                    const float* __restrict__ bias, float* __restrict__ outp) {
  __shared__ __attribute__((aligned(16))) u16 As[64 * LDSK64];
  __shared__ __attribute__((aligned(16))) u16 Bs[64 * LDSK64];
  const int tid = threadIdx.x;
  const int wave = tid >> 6, lane = tid & 63;
  const int quad = lane >> 4, col = lane & 15;
  const int m0 = blockIdx.x * 64;
  const int n0 = blockIdx.y * 64;
  const f32x4 zf = {0.f, 0.f, 0.f, 0.f};
  f32x4 acc[4] = {zf, zf, zf, zf};
  const int sr = tid >> 2, sk = (tid & 3) * 16;  // 64 rows x 64 k, 16 u16/thread
  for (int k0 = 0; k0 < ND; k0 += 64) {
    __syncthreads();
    *(uint4*)(&As[sr * LDSK64 + sk]) = *(const uint4*)(&A[(size_t)(m0 + sr) * ND + k0 + sk]);
    *(uint4*)(&As[sr * LDSK64 + sk + 8]) = *(const uint4*)(&A[(size_t)(m0 + sr) * ND + k0 + sk + 8]);
    *(uint4*)(&Bs[sr * LDSK64 + sk]) = *(const uint4*)(&Bt[(size_t)(n0 + sr) * ND + k0 + sk]);
    *(uint4*)(&Bs[sr * LDSK64 + sk + 8]) = *(const uint4*)(&Bt[(size_t)(n0 + sr) * ND + k0 + sk + 8]);
    __syncthreads();
    bf16x8 af0 = *(const bf16x8*)(&As[(wave * 16 + col) * LDSK64 + quad * 8]);
    bf16x8 af1 = *(const bf16x8*)(&As[(wave * 16 + col) * LDSK64 + 32 + quad * 8]);
    for (int nt = 0; nt < 4; nt++) {
      bf16x8 bf0 = *(const bf16x8*)(&Bs[(nt * 16 + col) * LDSK64 + quad * 8]);
      bf16x8 bf1 = *(const bf16x8*)(&Bs[(nt * 16 + col) * LDSK64 + 32 + quad * 8]);
      acc[nt] = __builtin_amdgcn_mfma_f32_16x16x32_bf16(af0, bf0, acc[nt], 0, 0, 0);
      acc[nt] = __builtin_amdgcn_mfma_f32_16x16x32_bf16(af1, bf1, acc[nt], 0, 0, 0);
    }
  }
  for (int nt = 0; nt < 4; nt++) {
    const int n = n0 + nt * 16 + col;
    const float bvv = bias[n];
    for (int r = 0; r < 4; r++) {
      const int m = m0 + wave * 16 + quad * 4 + r;
      outp[(size_t)m * ND + n] = acc[nt][r] + bvv;
    }
  }
}

// -------- important-row attention: gathered rows, pure causal, 8-way key-split, 64-key tiles --------
// 1-D grid, XCD swizzle: h = bid & 7 (K/V of head h stays in XCD-h L2).
// partials pbuf[((bh*8+chunk)*NILIST + row)*66] = {m, l, o[64] unnormalized}
__global__ __launch_bounds__(64) void csa_attn_imp(const u16* __restrict__ qb, const u16* __restrict__ kb,
                                                   const u16* __restrict__ vtb, const int* __restrict__ ilist,
                                                   float* __restrict__ pbuf) {
  const int lane = threadIdx.x;
  const int quad = lane >> 4, col = lane & 15;
  const int h = blockIdx.x & 7;         // XCD pin
  const int b = (blockIdx.x >> 3) & 1;
  const int rest = blockIdx.x >> 4;     // 0..159
  const int qt = rest % (NILIST / 16);
  const int chunk = rest / (NILIST / 16);
  const int bh = b * NH + h;

  const int* il = ilist + b * NILIST;
  const u16* qptr = qb + (size_t)(b * NH + h) * NS * NHD;
  const u16* kptr = kb + (size_t)(b * NH + h) * NS * NHD;
  const u16* vptr = vtb + (size_t)(b * NH + h) * NHD * NS;

  const int iq = il[qt * 16 + col];
  const int qrow = (iq < 0) ? 0 : iq;
  bf16x8 qf0 = *(const bf16x8*)(qptr + qrow * NHD + quad * 8);
  bf16x8 qf1 = *(const bf16x8*)(qptr + qrow * NHD + 32 + quad * 8);

  const f32x4 zf = {0.f, 0.f, 0.f, 0.f};
  float m_r[4], l_r[4];
  f32x4 of[4];
  int irow[4];
  for (int r = 0; r < 4; r++) {
    m_r[r] = -INFINITY;
    l_r[r] = 0.f;
    irow[r] = il[qt * 16 + quad * 4 + r];  // -1 for padding rows
  }
  for (int n = 0; n < 4; n++) of[n] = zf;

  __shared__ __attribute__((aligned(16))) u16 Pl[16 * PSTR];

  const int max_i = il[(qt * 16 + 15 > NKTOP - 1) ? (NKTOP - 1) : (qt * 16 + 15)];
  const int ntiles = (max_i >> 6) + 1;  // 64-key tiles
  for (int t = chunk; t < ntiles; t += NCHUNK) {
    const int j0 = t * 64;
    f32x4 cg[4];
    for (int g = 0; g < 4; g++) {
      const int jb = j0 + g * 16;
      bf16x8 k0f = *(const bf16x8*)(kptr + (jb + col) * NHD + quad * 8);
      bf16x8 k1f = *(const bf16x8*)(kptr + (jb + col) * NHD + 32 + quad * 8);
      f32x4 c = zf;
      c = __builtin_amdgcn_mfma_f32_16x16x32_bf16(qf0, k0f, c, 0, 0, 0);
      c = __builtin_amdgcn_mfma_f32_16x16x32_bf16(qf1, k1f, c, 0, 0, 0);
      cg[g] = c;
    }
    float ps[4][4], alpha[4];
    for (int r = 0; r < 4; r++) {
      const int i = irow[r];
      float s[4];
      float vmax = -INFINITY;
      for (int g = 0; g < 4; g++) {
        s[g] = (j0 + g * 16 + col <= i) ? cg[g][r] * 0.125f : -INFINITY;
        vmax = fmaxf(vmax, s[g]);
      }
      for (int off = 1; off < 16; off <<= 1) vmax = fmaxf(vmax, __shfl_xor(vmax, off, 64));
      float newm = fmaxf(m_r[r], vmax);
      bool dead = (newm == -INFINITY);
      float a = dead ? 1.f : __expf(m_r[r] - newm);
      float psum = 0.f;
      for (int g = 0; g < 4; g++) {
        float p = dead ? 0.f : __expf(s[g] - newm);
        ps[r][g] = p;
        psum += p;
      }
      for (int off = 1; off < 16; off <<= 1) psum += __shfl_xor(psum, off, 64);
      m_r[r] = newm;
      l_r[r] = l_r[r] * a + psum;
      alpha[r] = a;
    }
    for (int n = 0; n < 4; n++)
      for (int r = 0; r < 4; r++) of[n][r] *= alpha[r];
    __syncthreads();
    for (int r = 0; r < 4; r++)
      for (int g = 0; g < 4; g++)
        Pl[(quad * 4 + r) * PSTR + g * 16 + col] = f2bf(ps[r][g]);
    __syncthreads();
    bf16x8 pf0 = *(const bf16x8*)(&Pl[col * PSTR + quad * 8]);
    bf16x8 pf1 = *(const bf16x8*)(&Pl[col * PSTR + 32 + quad * 8]);
    for (int vn = 0; vn < 4; vn++) {
      bf16x8 vf0 = *(const bf16x8*)(vptr + (size_t)(vn * 16 + col) * NS + j0 + quad * 8);
      bf16x8 vf1 = *(const bf16x8*)(vptr + (size_t)(vn * 16 + col) * NS + j0 + 32 + quad * 8);
      of[vn] = __builtin_amdgcn_mfma_f32_16x16x32_bf16(pf0, vf0, of[vn], 0, 0, 0);
      of[vn] = __builtin_amdgcn_mfma_f32_16x16x32_bf16(pf1, vf1, of[vn], 0, 0, 0);
    }
  }
  float* pr = pbuf + ((size_t)(bh * NCHUNK + chunk) * NILIST + qt * 16) * 66;
  for (int r = 0; r < 4; r++) {
    const int row = quad * 4 + r;
    if (col == 0) {
      pr[row * 66 + 0] = m_r[r];
      pr[row * 66 + 1] = l_r[r];
    }
    for (int vn = 0; vn < 4; vn++)
      pr[row * 66 + 2 + vn * 16 + col] = of[vn][r];
  }
}

// -------- merge important-row partials --------
__global__ __launch_bounds__(64) void csa_merge(const float* __restrict__ pbuf, const int* __restrict__ ilist,
                                                u16* __restrict__ attnb) {
  const int kp = blockIdx.x, h = blockIdx.y, b = blockIdx.z;
  const int lane = threadIdx.x;  // = d
  const int z = b * NH + h;
  float mc[NCHUNK], lc[NCHUNK], mstar = -INFINITY;
  for (int c = 0; c < NCHUNK; c++) {
    const float* base = pbuf + ((size_t)(z * NCHUNK + c) * NILIST + kp) * 66;
    mc[c] = base[0];
    lc[c] = base[1];
    mstar = fmaxf(mstar, mc[c]);
  }
  float lsum = 0.f, osum = 0.f;
  for (int c = 0; c < NCHUNK; c++) {
    const float* base = pbuf + ((size_t)(z * NCHUNK + c) * NILIST + kp) * 66;
    float w = (mc[c] == -INFINITY) ? 0.f : __expf(mc[c] - mstar);
    lsum += w * lc[c];
    osum += w * base[2 + lane];
  }
  const int i = ilist[b * NILIST + kp];
  attnb[((size_t)(b * NS + i) * NH + h) * NHD + lane] = f2bf(osum / lsum);
}

// -------- sparse-row attention: non-important rows, 2 lanes/key + diag, 1 wave/(row,head) --------
// 1-D grid, XCD swizzle: h = bid & 7 (K/V of head h stays in XCD-h L2). LDS p/j version
// (round-6 structure: low VGPR, high occupancy — kernel is L2-miss-latency bound).
__global__ __launch_bounds__(256) void csa_attn_sparse(const u16* __restrict__ qb, const u16* __restrict__ kb,
                                                       const u16* __restrict__ vb, const int* __restrict__ nlist,
                                                       const int* __restrict__ rand_idx, u16* __restrict__ attnb) {
  __shared__ __attribute__((aligned(16))) u16 ql[4][64];
  __shared__ float pl[4][33];
  __shared__ int jl[4][33];
  const int wave = threadIdx.x >> 6, lane = threadIdx.x & 63;
  const int h = blockIdx.x & 7;         // XCD pin
  const int b = (blockIdx.x >> 3) & 1;
  const int slot = (blockIdx.x >> 4) * 4 + wave;
  const int i = nlist[b * NSPAD + slot];  // -1 for the 3 pad slots
  const int iv = (i < 0) ? 0 : i;

  const u16* qrow = qb + ((size_t)(b * NH + h) * NS + iv) * NHD;
  const u16* kbase = kb + (size_t)(b * NH + h) * NS * NHD;
  const u16* vbase = vb + (size_t)(b * NH + h) * NS * NHD;

  // stage q into LDS (8 lanes x 16B)
  if (lane < 8) *(bf16x8*)(&ql[wave][lane * 8]) = *(const bf16x8*)(qrow + lane * 8);
  __syncthreads();

  // --- diagonal key j=i (always valid): lane = dim, full-wave reduce ---
  float sd = bf2f((short)ql[wave][lane]) * bf2f((short)kbase[(size_t)iv * NHD + lane]);
  for (int off = 1; off < 64; off <<= 1) sd += __shfl_xor(sd, off, 64);
  sd *= 0.125f;

  // --- 32 candidate keys, 2 lanes per key (half = 32 dims each) ---
  const int c = lane >> 1, half = lane & 1;
  int j, valid;
  if (c < 16) {
    j = i - NHWIN + c;  // window j = i-16 .. i-1
    valid = (j >= 0);
  } else {
    const int* rr = rand_idx + ((size_t)b * NS + iv) * NRC;
    const int cr = c - 16;
    j = rr[cr];
    valid = (j <= i - NHWIN - 1);  // causal AND strictly below window
    for (int cp = 0; cp < cr; cp++) valid &= (rr[cp] != j);  // first occurrence wins
  }
  const int jr = valid ? j : 0;
  float s = 0.f;
  {
    const u16* krow = kbase + (size_t)jr * NHD + half * 32;
    for (int c8 = 0; c8 < 4; c8++) {
      bf16x8 kv = *(const bf16x8*)(krow + c8 * 8);
      bf16x8 qv = *(const bf16x8*)(&ql[wave][half * 32 + c8 * 8]);
      for (int e = 0; e < 8; e++) s += bf2f(qv[e]) * bf2f(kv[e]);
    }
  }
  s += __shfl_xor(s, 1, 64);  // combine halves; both lanes of pair hold full dot
  s = valid ? s * 0.125f : -INFINITY;

  // --- softmax over {32 candidates} U {diag} ---
  float smax = s;
  for (int off = 1; off < 64; off <<= 1) smax = fmaxf(smax, __shfl_xor(smax, off, 64));
  smax = fmaxf(smax, sd);
  float p = valid ? __expf(s - smax) : 0.f;
  float pd = __expf(sd - smax);
  float pm = (half == 0) ? p : 0.f;
  for (int off = 1; off < 64; off <<= 1) pm += __shfl_xor(pm, off, 64);
  const float lsum = pm + pd;

  if (half == 0) {
    pl[wave][c] = p;
    jl[wave][c] = jr;
  }
  if (lane == 0) {
    pl[wave][32] = pd;
    jl[wave][32] = iv;
  }
  __syncthreads();

  // --- PV: lane = output dim; key index wave-uniform -> SGPR base via readfirstlane ---
  float o = 0.f;
  for (int jj = 0; jj < 33; jj++) {
    const int jk = __builtin_amdgcn_readfirstlane(jl[wave][jj]);
    const float pj = pl[wave][jj];
    o += pj * bf2f((short)vbase[(size_t)jk * NHD + lane]);
  }
  if (i >= 0)
    attnb[((size_t)(b * NS + i) * NH + h) * NHD + lane] = f2bf(o / lsum);
}

extern "C" void kernel_launch(void* const* d_in, const int* in_sizes, int n_in,
                              void* d_out, int out_size, void* d_ws, size_t ws_size,
                              hipStream_t stream) {
  const float* x = (const float*)d_in[0];
  const float* bq = (const float*)d_in[2];
  const float* bk = (const float*)d_in[4];
  const float* bv = (const float*)d_in[6];
  const float* bo = (const float*)d_in[8];
  const float* Ws1 = (const float*)d_in[9];
  const float* bs1 = (const float*)d_in[10];
  const float* Ws2 = (const float*)d_in[11];
  const int* rand_idx = (const int*)d_in[13];
  float* out = (float*)d_out;

  // workspace layout (~37 MB)
  char* p = (char*)d_ws;
  u16* wt = (u16*)p;         p += (size_t)4 * ND * ND * 2;         // 2 MB  [Wq^T;Wk^T;Wv^T;Wo^T] bf16
  u16* xb = (u16*)p;         p += (size_t)NB * NS * ND * 2;        // 4 MB x bf16 [4096,512]
  u16* qbuf = (u16*)p;       p += (size_t)NB * NH * NS * NHD * 2;  // 4 MB [B,H,S,HD]
  u16* kbuf = (u16*)p;       p += (size_t)NB * NH * NS * NHD * 2;  // 4 MB
  u16* vtbuf = (u16*)p;      p += (size_t)NB * NH * NHD * NS * 2;  // 4 MB [B,H,HD,S]
  u16* vbuf = (u16*)p;       p += (size_t)NB * NH * NS * NHD * 2;  // 4 MB [B,H,S,HD]
  u16* attnb = (u16*)p;      p += (size_t)NB * NS * ND * 2;        // 4 MB [B,S,H,HD]
  float* part = (float*)p;   p += (size_t)NB * NS * 4 * 4;         // 64 KB logit partials
  int* rowimp = (int*)p;     p += (size_t)NB * NS * 4;
  int* ilist = (int*)p;      p += (size_t)NB * NILIST * 4;
  int* nlist = (int*)p;      p += (size_t)NB * NSPAD * 4;
  float* pbuf = (float*)p;   // 10.8 MB partials

  // scorer + weight transpose + x conversion (one launch; scorer first - it gates the rank chain)
  csa_prep<<<dim3(1792), 256, 0, stream>>>((const float*)d_in[1], (const float*)d_in[3],
                                           (const float*)d_in[5], (const float*)d_in[7], wt,
                                           x, xb, Ws1, bs1, Ws2, part);
  csa_rank<<<dim3(NS / 8, NB), 256, 0, stream>>>(part, rowimp);
  csa_ilist<<<dim3(NB), 256, 0, stream>>>(rowimp, ilist, nlist);

  // fused QKV projection (pure bf16 GEMM, head->XCD swizzled)
  csa_gemm_qkv<<<dim3(768), 256, 0, stream>>>(xb, wt, bq, bk, bv, qbuf, kbuf, vtbuf, vbuf);

  // attention: important rows (MFMA, 8-way split-K) + sparse rows (per-wave), both head->XCD swizzled
  csa_attn_imp<<<dim3(2560), 64, 0, stream>>>(qbuf, kbuf, vtbuf, ilist, pbuf);
  csa_attn_sparse<<<dim3((NSPAD / 4) * NH * NB), 256, 0, stream>>>(qbuf, kbuf, vbuf, nlist, rand_idx, attnb);
  csa_merge<<<dim3(NKTOP, NH, NB), 64, 0, stream>>>(pbuf, ilist, attnb);

  // output projection
  csa_gemm_out<<<dim3(64, 8), 256, 0, stream>>>(attnb, wt + 3 * (size_t)ND * ND, bo, out);
}

// Round 10
// 198.780 us; speedup vs baseline: 1.0953x; 1.0063x over previous
//
#include <hip/hip_runtime.h>
#include <math.h>

typedef unsigned short u16;
typedef unsigned int u32;
typedef unsigned long long u64;
typedef short bf16x8 __attribute__((ext_vector_type(8)));
typedef float f32x4 __attribute__((ext_vector_type(4)));

constexpr int NB = 2, NS = 2048, ND = 512, NH = 8, NHD = 64;
constexpr int NKTOP = 307, NHWIN = 16, NRC = 16;
constexpr int NILIST = 320;        // 20 tiles of 16 (padded with -1)
constexpr int NSPAR = NS - NKTOP;  // 1741 non-important rows (exact: rank is a permutation)
constexpr int NSPAD = 1744;        // padded to multiple of 4
constexpr int NCHUNK = 8;          // key-split factor for important-row attention
constexpr int LDSK64 = 72;         // 144B row stride for 64-k tiles
constexpr int PSTR = 72;           // P-tile row stride (16 rows x 64 keys)
constexpr int NSPB = (NSPAD / 4) * NH * NB;  // 6976 sparse blocks
constexpr int NMRG = NKTOP * NH * NB / 4;    // 1228 merge blocks (4 rows each; 4912 = 1228*4 exact)

__device__ __forceinline__ u16 f2bf(float f) {
  u32 u = __builtin_bit_cast(u32, f);
  u32 r = (u + 0x7FFFu + ((u >> 16) & 1u)) >> 16;  // RNE
  return (u16)r;
}
__device__ __forceinline__ float bf2f(short v) {
  return __builtin_bit_cast(float, (u32)(u16)v << 16);
}

// -------- fused prep: scorer (0..255) + weight transpose (256..767) + x cvt (768..1791) --------
// scorer: part[row][ny] = relu(x@Ws1+bs1).Ws2 over 64-col slice (fp32).
// sigmoid and bs2 are strictly monotone / constant -> ranking on raw logits is identical.
__global__ __launch_bounds__(256) void csa_prep(const float* __restrict__ W0, const float* __restrict__ W1,
                                                const float* __restrict__ W2, const float* __restrict__ W3,
                                                u16* __restrict__ wt, const float* __restrict__ x,
                                                u16* __restrict__ xb, const float* __restrict__ Ws1,
                                                const float* __restrict__ bs1, const float* __restrict__ Ws2,
                                                float* __restrict__ part) {
  __shared__ float sh[2 * 32 * 68];  // 17.4 KB: scorer As+Bs; cvt tile (64x33) fits too
  const int tid = threadIdx.x;
  if (blockIdx.x < 256) {
    // ---- scorer 64x64 tile ----
    const int m0 = (blockIdx.x & 63) * 64, n0 = (blockIdx.x >> 6) * 64;
    float(*As)[68] = (float(*)[68])sh;
    float(*Bs)[68] = (float(*)[68])(sh + 32 * 68);
    const int ty = tid >> 4, tx = tid & 15;
    float acc[4][4] = {};
    const int arow = tid & 63, aks = (tid >> 6) * 8;
    const int bk = tid >> 3, bc = (tid & 7) * 8;
    for (int k0 = 0; k0 < ND; k0 += 32) {
      __syncthreads();
      {
        float4 a0 = *(const float4*)(&x[(size_t)(m0 + arow) * ND + k0 + aks]);
        float4 a1 = *(const float4*)(&x[(size_t)(m0 + arow) * ND + k0 + aks + 4]);
        As[aks + 0][arow] = a0.x; As[aks + 1][arow] = a0.y;
        As[aks + 2][arow] = a0.z; As[aks + 3][arow] = a0.w;
        As[aks + 4][arow] = a1.x; As[aks + 5][arow] = a1.y;
        As[aks + 6][arow] = a1.z; As[aks + 7][arow] = a1.w;
      }
      *(float4*)(&Bs[bk][bc]) = *(const float4*)(&Ws1[(size_t)(k0 + bk) * 256 + n0 + bc]);
      *(float4*)(&Bs[bk][bc + 4]) = *(const float4*)(&Ws1[(size_t)(k0 + bk) * 256 + n0 + bc + 4]);
      __syncthreads();
      for (int k = 0; k < 32; k++) {
        float4 av = *(const float4*)(&As[k][ty * 4]);
        float4 bv = *(const float4*)(&Bs[k][tx * 4]);
        float aa[4] = {av.x, av.y, av.z, av.w};
        float bb[4] = {bv.x, bv.y, bv.z, bv.w};
        for (int i = 0; i < 4; i++)
          for (int j = 0; j < 4; j++)
            acc[i][j] += aa[i] * bb[j];
      }
    }
    float4 w2 = *(const float4*)(&Ws2[n0 + tx * 4]);
    float4 b1 = *(const float4*)(&bs1[n0 + tx * 4]);
    for (int i = 0; i < 4; i++) {
      float p = fmaxf(acc[i][0] + b1.x, 0.f) * w2.x + fmaxf(acc[i][1] + b1.y, 0.f) * w2.y +
                fmaxf(acc[i][2] + b1.z, 0.f) * w2.z + fmaxf(acc[i][3] + b1.w, 0.f) * w2.w;
      for (int off = 1; off < 16; off <<= 1) p += __shfl_xor(p, off, 64);
      if (tx == 0) part[(size_t)(m0 + ty * 4 + i) * 4 + (blockIdx.x >> 6)] = p;
    }
  } else if (blockIdx.x < 768) {
    // ---- weight transpose: W[K][N] fp32 -> Wt[N][K] bf16, 128B packed writes ----
    const int cb = blockIdx.x - 256;
    const int w = cb >> 7;
    const int kb = ((cb & 127) >> 4) * 64;
    const int nb = (cb & 15) * 32;
    const float* src = (w == 0) ? W0 : (w == 1) ? W1 : (w == 2) ? W2 : W3;
    float(*tile)[33] = (float(*)[33])sh;
    int tx = tid & 31, ty = tid >> 5;
    for (int i = ty; i < 64; i += 8) tile[i][tx] = src[(size_t)(kb + i) * ND + nb + tx];
    __syncthreads();
    u16* dst = wt + (size_t)w * ND * ND;
    for (int n = ty; n < 32; n += 8) {
      u32 pk = (u32)f2bf(tile[2 * tx][n]) | ((u32)f2bf(tile[2 * tx + 1][n]) << 16);
      *(u32*)(&dst[(size_t)(nb + n) * ND + kb + 2 * tx]) = pk;
    }
  } else {
    // ---- x fp32 -> bf16, one-time (removes 24x redundant conversion in qkv staging) ----
    const int i = ((blockIdx.x - 768) * 256 + tid) * 8;
    float4 v0 = *(const float4*)(x + i);
    float4 v1 = *(const float4*)(x + i + 4);
    u32 o0 = (u32)f2bf(v0.x) | ((u32)f2bf(v0.y) << 16);
    u32 o1 = (u32)f2bf(v0.z) | ((u32)f2bf(v0.w) << 16);
    u32 o2 = (u32)f2bf(v1.x) | ((u32)f2bf(v1.y) << 16);
    u32 o3 = (u32)f2bf(v1.z) | ((u32)f2bf(v1.w) << 16);
    uint4 o = {o0, o1, o2, o3};
    *(uint4*)(xb + i) = o;
  }
}

// -------- exact top-k on logits (lax.top_k tie semantics: lower index wins), wave per 2 rows --------
__global__ __launch_bounds__(256) void csa_rank(const float* __restrict__ part, int* __restrict__ rowimp) {
  __shared__ float vals[NS];
  const int b = blockIdx.y;
  {
    int t8 = threadIdx.x * 8;
    for (int e = 0; e < 8; e++) {
      float4 pp = *(const float4*)(&part[(size_t)(b * NS + t8 + e) * 4]);
      vals[t8 + e] = (pp.x + pp.y) + (pp.z + pp.w);  // fixed order -> deterministic
    }
  }
  __syncthreads();
  const int wave = threadIdx.x >> 6, lane = threadIdx.x & 63;
  const int s0 = blockIdx.x * 8 + wave * 2;  // two rows per wave
  const int s1 = s0 + 1;
  const float v0 = vals[s0], v1 = vals[s1];
  int r0 = 0, r1 = 0;
  for (int t = lane; t < NS; t += 64) {
    float u = vals[t];
    r0 += (int)((u > v0) | ((u == v0) & (t < s0)));
    r1 += (int)((u > v1) | ((u == v1) & (t < s1)));
  }
  for (int off = 1; off < 64; off <<= 1) {
    r0 += __shfl_xor(r0, off, 64);
    r1 += __shfl_xor(r1, off, 64);
  }
  if (lane == 0) {
    rowimp[b * NS + s0] = (r0 < NKTOP) ? 1 : 0;
    rowimp[b * NS + s1] = (r1 < NKTOP) ? 1 : 0;
  }
}

// -------- fused QKV projection (blocks 0..767) + row-list compaction (blocks 768..769) --------
// qkv: pure bf16 MFMA, 128x64 tile, K=64 stages, N=1536. 1-D grid, XCD swizzle: head = bid & 7.
// ilist: compact important rows (and complement) into sorted lists (depends on rank, runs here).
__global__ __launch_bounds__(256) void csa_gemm_qkv(const u16* __restrict__ xb, const u16* __restrict__ Bt,
                                                    const float* __restrict__ bq, const float* __restrict__ bk,
                                                    const float* __restrict__ bv, u16* __restrict__ qb,
                                                    u16* __restrict__ kb, u16* __restrict__ vtb,
                                                    u16* __restrict__ vb, const int* __restrict__ rowimp,
                                                    int* __restrict__ ilist, int* __restrict__ nlist) {
  __shared__ __attribute__((aligned(16))) u16 As[128 * LDSK64];  // 18.4 KB
  __shared__ __attribute__((aligned(16))) u16 Bs[64 * LDSK64];   // 9.2 KB
  const int tid = threadIdx.x;
  if (blockIdx.x >= 768) {
    // ---- ilist: prefix-sum compaction, one block per batch ----
    int* cs = (int*)As;
    const int b = blockIdx.x - 768;
    const int t = tid;
    int flags[8], sum = 0;
    for (int k = 0; k < 8; k++) {
      flags[k] = rowimp[b * NS + t * 8 + k];
      sum += flags[k];
    }
    cs[t] = sum;
    __syncthreads();
    for (int off = 1; off < 256; off <<= 1) {
      int v = (t >= off) ? cs[t - off] : 0;
      __syncthreads();
      cs[t] += v;
      __syncthreads();
    }
    int pos = cs[t] - sum;  // important rows before t*8
    for (int k = 0; k < 8; k++) {
      int r = t * 8 + k;
      if (flags[k]) ilist[b * NILIST + pos++] = r;
      else nlist[b * NSPAD + (r - pos)] = r;  // r - pos = non-important rows before r
    }
    if (t < NILIST - NKTOP) ilist[b * NILIST + NKTOP + t] = -1;
    if (t < NSPAD - NSPAR) nlist[b * NSPAD + NSPAR + t] = -1;
    return;
  }
  const int wave = tid >> 6, lane = tid & 63;
  const int quad = lane >> 4, col = lane & 15;
  const int hsw = blockIdx.x & 7;          // head (XCD pin)
  const int rest = blockIdx.x >> 3;        // 0..95
  const int w = rest >> 5;                 // 0=Q 1=K 2=V
  const int m0 = (rest & 31) * 128;
  const int n0 = (w * 8 + hsw) * 64;
  const f32x4 zf = {0.f, 0.f, 0.f, 0.f};
  f32x4 acc[2][4] = {{zf, zf, zf, zf}, {zf, zf, zf, zf}};
  const int sar = tid >> 1, sak = (tid & 1) * 32;  // A: 128 rows x 64 k, 32 u16/thread
  const int sbr = tid >> 2, sbk = (tid & 3) * 16;  // B: 64 rows x 64 k, 16 u16/thread
  for (int k0 = 0; k0 < ND; k0 += 64) {
    __syncthreads();
    {
      const u16* xp = &xb[(size_t)(m0 + sar) * ND + k0 + sak];
      u16* ap = &As[sar * LDSK64 + sak];
      *(uint4*)(ap) = *(const uint4*)(xp);
      *(uint4*)(ap + 8) = *(const uint4*)(xp + 8);
      *(uint4*)(ap + 16) = *(const uint4*)(xp + 16);
      *(uint4*)(ap + 24) = *(const uint4*)(xp + 24);
    }
    *(uint4*)(&Bs[sbr * LDSK64 + sbk]) = *(const uint4*)(&Bt[(size_t)(n0 + sbr) * ND + k0 + sbk]);
    *(uint4*)(&Bs[sbr * LDSK64 + sbk + 8]) = *(const uint4*)(&Bt[(size_t)(n0 + sbr) * ND + k0 + sbk + 8]);
    __syncthreads();
    bf16x8 af[2][2];
    for (int r = 0; r < 2; r++)
      for (int hh = 0; hh < 2; hh++)
        af[r][hh] = *(const bf16x8*)(&As[(wave * 32 + r * 16 + col) * LDSK64 + hh * 32 + quad * 8]);
    for (int c = 0; c < 4; c++) {
      bf16x8 b0 = *(const bf16x8*)(&Bs[(c * 16 + col) * LDSK64 + quad * 8]);
      bf16x8 b1 = *(const bf16x8*)(&Bs[(c * 16 + col) * LDSK64 + 32 + quad * 8]);
      acc[0][c] = __builtin_amdgcn_mfma_f32_16x16x32_bf16(af[0][0], b0, acc[0][c], 0, 0, 0);
      acc[0][c] = __builtin_amdgcn_mfma_f32_16x16x32_bf16(af[0][1], b1, acc[0][c], 0, 0, 0);
      acc[1][c] = __builtin_amdgcn_mfma_f32_16x16x32_bf16(af[1][0], b0, acc[1][c], 0, 0, 0);
      acc[1][c] = __builtin_amdgcn_mfma_f32_16x16x32_bf16(af[1][1], b1, acc[1][c], 0, 0, 0);
    }
  }
  const float* bias = (w == 0) ? bq : (w == 1) ? bk : bv;
  for (int c = 0; c < 4; c++) {
    const int ng = n0 + c * 16 + col;
    const int nn = ng & 511, hh = nn >> 6, hd = nn & 63;
    const float bvv = bias[nn];
    for (int r = 0; r < 2; r++) {
      for (int rr = 0; rr < 4; rr++) {
        const int m = m0 + wave * 32 + r * 16 + quad * 4 + rr;
        const int bb = m >> 11, s = m & (NS - 1);
        u16 v16 = f2bf(acc[r][c][rr] + bvv);
        if (w == 0) qb[((size_t)(bb * NH + hh) * NS + s) * NHD + hd] = v16;
        else if (w == 1) kb[((size_t)(bb * NH + hh) * NS + s) * NHD + hd] = v16;
        else {
          vtb[((size_t)(bb * NH + hh) * NHD + hd) * NS + s] = v16;
          vb[((size_t)(bb * NH + hh) * NS + s) * NHD + hd] = v16;
        }
      }
    }
  }
}

// -------- output projection: bf16 MFMA 64x64 tile, K=64 stages, fp32 out --------
__global__ __launch_bounds__(256) void csa_gemm_out(const u16* __restrict__ A, const u16* __restrict__ Bt,
                                                    const float* __restrict__ bias, float* __restrict__ outp) {
  __shared__ __attribute__((aligned(16))) u16 As[64 * LDSK64];
  __shared__ __attribute__((aligned(16))) u16 Bs[64 * LDSK64];
  const int tid = threadIdx.x;
  const int wave = tid >> 6, lane = tid & 63;
  const int quad = lane >> 4, col = lane & 15;
  const int m0 = blockIdx.x * 64;
  const int n0 = blockIdx.y * 64;
  const f32x4 zf = {0.f, 0.f, 0.f, 0.f};
  f32x4 acc[4] = {zf, zf, zf, zf};
  const int sr = tid >> 2, sk = (tid & 3) * 16;  // 64 rows x 64 k, 16 u16/thread
  for (int k0 = 0; k0 < ND; k0 += 64) {
    __syncthreads();
    *(uint4*)(&As[sr * LDSK64 + sk]) = *(const uint4*)(&A[(size_t)(m0 + sr) * ND + k0 + sk]);
    *(uint4*)(&As[sr * LDSK64 + sk + 8]) = *(const uint4*)(&A[(size_t)(m0 + sr) * ND + k0 + sk + 8]);
    *(uint4*)(&Bs[sr * LDSK64 + sk]) = *(const uint4*)(&Bt[(size_t)(n0 + sr) * ND + k0 + sk]);
    *(uint4*)(&Bs[sr * LDSK64 + sk + 8]) = *(const uint4*)(&Bt[(size_t)(n0 + sr) * ND + k0 + sk + 8]);
    __syncthreads();
    bf16x8 af0 = *(const bf16x8*)(&As[(wave * 16 + col) * LDSK64 + quad * 8]);
    bf16x8 af1 = *(const bf16x8*)(&As[(wave * 16 + col) * LDSK64 + 32 + quad * 8]);
    for (int nt = 0; nt < 4; nt++) {
      bf16x8 bf0 = *(const bf16x8*)(&Bs[(nt * 16 + col) * LDSK64 + quad * 8]);
      bf16x8 bf1 = *(const bf16x8*)(&Bs[(nt * 16 + col) * LDSK64 + 32 + quad * 8]);
      acc[nt] = __builtin_amdgcn_mfma_f32_16x16x32_bf16(af0, bf0, acc[nt], 0, 0, 0);
      acc[nt] = __builtin_amdgcn_mfma_f32_16x16x32_bf16(af1, bf1, acc[nt], 0, 0, 0);
    }
  }
  for (int nt = 0; nt < 4; nt++) {
    const int n = n0 + nt * 16 + col;
    const float bvv = bias[n];
    for (int r = 0; r < 4; r++) {
      const int m = m0 + wave * 16 + quad * 4 + r;
      outp[(size_t)m * ND + n] = acc[nt][r] + bvv;
    }
  }
}

// -------- important-row attention: gathered rows, pure causal, 8-way key-split, 64-key tiles --------
// 1-D grid, XCD swizzle: h = bid & 7 (K/V of head h stays in XCD-h L2).
// partials pbuf[((bh*8+chunk)*NILIST + row)*66] = {m, l, o[64] unnormalized}
__global__ __launch_bounds__(64) void csa_attn_imp(const u16* __restrict__ qb, const u16* __restrict__ kb,
                                                   const u16* __restrict__ vtb, const int* __restrict__ ilist,
                                                   float* __restrict__ pbuf) {
  const int lane = threadIdx.x;
  const int quad = lane >> 4, col = lane & 15;
  const int h = blockIdx.x & 7;         // XCD pin
  const int b = (blockIdx.x >> 3) & 1;
  const int rest = blockIdx.x >> 4;     // 0..159
  const int qt = rest % (NILIST / 16);
  const int chunk = rest / (NILIST / 16);
  const int bh = b * NH + h;

  const int* il = ilist + b * NILIST;
  const u16* qptr = qb + (size_t)(b * NH + h) * NS * NHD;
  const u16* kptr = kb + (size_t)(b * NH + h) * NS * NHD;
  const u16* vptr = vtb + (size_t)(b * NH + h) * NHD * NS;

  const int iq = il[qt * 16 + col];
  const int qrow = (iq < 0) ? 0 : iq;
  bf16x8 qf0 = *(const bf16x8*)(qptr + qrow * NHD + quad * 8);
  bf16x8 qf1 = *(const bf16x8*)(qptr + qrow * NHD + 32 + quad * 8);

  const f32x4 zf = {0.f, 0.f, 0.f, 0.f};
  float m_r[4], l_r[4];
  f32x4 of[4];
  int irow[4];
  for (int r = 0; r < 4; r++) {
    m_r[r] = -INFINITY;
    l_r[r] = 0.f;
    irow[r] = il[qt * 16 + quad * 4 + r];  // -1 for padding rows
  }
  for (int n = 0; n < 4; n++) of[n] = zf;

  __shared__ __attribute__((aligned(16))) u16 Pl[16 * PSTR];

  const int max_i = il[(qt * 16 + 15 > NKTOP - 1) ? (NKTOP - 1) : (qt * 16 + 15)];
  const int ntiles = (max_i >> 6) + 1;  // 64-key tiles
  for (int t = chunk; t < ntiles; t += NCHUNK) {
    const int j0 = t * 64;
    f32x4 cg[4];
    for (int g = 0; g < 4; g++) {
      const int jb = j0 + g * 16;
      bf16x8 k0f = *(const bf16x8*)(kptr + (jb + col) * NHD + quad * 8);
      bf16x8 k1f = *(const bf16x8*)(kptr + (jb + col) * NHD + 32 + quad * 8);
      f32x4 c = zf;
      c = __builtin_amdgcn_mfma_f32_16x16x32_bf16(qf0, k0f, c, 0, 0, 0);
      c = __builtin_amdgcn_mfma_f32_16x16x32_bf16(qf1, k1f, c, 0, 0, 0);
      cg[g] = c;
    }
    float ps[4][4], alpha[4];
    for (int r = 0; r < 4; r++) {
      const int i = irow[r];
      float s[4];
      float vmax = -INFINITY;
      for (int g = 0; g < 4; g++) {
        s[g] = (j0 + g * 16 + col <= i) ? cg[g][r] * 0.125f : -INFINITY;
        vmax = fmaxf(vmax, s[g]);
      }
      for (int off = 1; off < 16; off <<= 1) vmax = fmaxf(vmax, __shfl_xor(vmax, off, 64));
      float newm = fmaxf(m_r[r], vmax);
      bool dead = (newm == -INFINITY);
      float a = dead ? 1.f : __expf(m_r[r] - newm);
      float psum = 0.f;
      for (int g = 0; g < 4; g++) {
        float p = dead ? 0.f : __expf(s[g] - newm);
        ps[r][g] = p;
        psum += p;
      }
      for (int off = 1; off < 16; off <<= 1) psum += __shfl_xor(psum, off, 64);
      m_r[r] = newm;
      l_r[r] = l_r[r] * a + psum;
      alpha[r] = a;
    }
    for (int n = 0; n < 4; n++)
      for (int r = 0; r < 4; r++) of[n][r] *= alpha[r];
    __syncthreads();
    for (int r = 0; r < 4; r++)
      for (int g = 0; g < 4; g++)
        Pl[(quad * 4 + r) * PSTR + g * 16 + col] = f2bf(ps[r][g]);
    __syncthreads();
    bf16x8 pf0 = *(const bf16x8*)(&Pl[col * PSTR + quad * 8]);
    bf16x8 pf1 = *(const bf16x8*)(&Pl[col * PSTR + 32 + quad * 8]);
    for (int vn = 0; vn < 4; vn++) {
      bf16x8 vf0 = *(const bf16x8*)(vptr + (size_t)(vn * 16 + col) * NS + j0 + quad * 8);
      bf16x8 vf1 = *(const bf16x8*)(vptr + (size_t)(vn * 16 + col) * NS + j0 + 32 + quad * 8);
      of[vn] = __builtin_amdgcn_mfma_f32_16x16x32_bf16(pf0, vf0, of[vn], 0, 0, 0);
      of[vn] = __builtin_amdgcn_mfma_f32_16x16x32_bf16(pf1, vf1, of[vn], 0, 0, 0);
    }
  }
  float* pr = pbuf + ((size_t)(bh * NCHUNK + chunk) * NILIST + qt * 16) * 66;
  for (int r = 0; r < 4; r++) {
    const int row = quad * 4 + r;
    if (col == 0) {
      pr[row * 66 + 0] = m_r[r];
      pr[row * 66 + 1] = l_r[r];
    }
    for (int vn = 0; vn < 4; vn++)
      pr[row * 66 + 2 + vn * 16 + col] = of[vn][r];
  }
}

// -------- fused: sparse-row attention (blocks 0..NSPB-1) + imp-partial merge (NSPB..NSPB+NMRG-1) ----
// sparse: non-important rows, 2 lanes/key + diag, 1 wave/(row,head); XCD swizzle h = bid & 7.
// merge: reads pbuf (written by csa_attn_imp, previous launch); disjoint attnb rows vs sparse.
__global__ __launch_bounds__(256) void csa_attn_sparse(const u16* __restrict__ qb, const u16* __restrict__ kb,
                                                       const u16* __restrict__ vb, const int* __restrict__ nlist,
                                                       const int* __restrict__ rand_idx,
                                                       const float* __restrict__ pbuf,
                                                       const int* __restrict__ ilist, u16* __restrict__ attnb) {
  __shared__ __attribute__((aligned(16))) u16 ql[4][64];
  __shared__ float pl[4][33];
  __shared__ int jl[4][33];
  const int wave = threadIdx.x >> 6, lane = threadIdx.x & 63;
  if (blockIdx.x >= NSPB) {
    // ---- merge important-row partials: 4 (kp,h,b) units per block, one per wave ----
    const int mu = (blockIdx.x - NSPB) * 4 + wave;  // 0..4911
    const int kp = mu % NKTOP;
    const int h = (mu / NKTOP) & 7;
    const int b = mu / (NKTOP * NH);
    const int z = b * NH + h;
    float mc[NCHUNK], lc[NCHUNK], mstar = -INFINITY;
    for (int c = 0; c < NCHUNK; c++) {
      const float* base = pbuf + ((size_t)(z * NCHUNK + c) * NILIST + kp) * 66;
      mc[c] = base[0];
      lc[c] = base[1];
      mstar = fmaxf(mstar, mc[c]);
    }
    float lsum = 0.f, osum = 0.f;
    for (int c = 0; c < NCHUNK; c++) {
      const float* base = pbuf + ((size_t)(z * NCHUNK + c) * NILIST + kp) * 66;
      float w = (mc[c] == -INFINITY) ? 0.f : __expf(mc[c] - mstar);
      lsum += w * lc[c];
      osum += w * base[2 + lane];
    }
    const int i = ilist[b * NILIST + kp];
    attnb[((size_t)(b * NS + i) * NH + h) * NHD + lane] = f2bf(osum / lsum);
    return;
  }
  const int h = blockIdx.x & 7;         // XCD pin
  const int b = (blockIdx.x >> 3) & 1;
  const int slot = (blockIdx.x >> 4) * 4 + wave;
  const int i = nlist[b * NSPAD + slot];  // -1 for the 3 pad slots
  const int iv = (i < 0) ? 0 : i;

  const u16* qrow = qb + ((size_t)(b * NH + h) * NS + iv) * NHD;
  const u16* kbase = kb + (size_t)(b * NH + h) * NS * NHD;
  const u16* vbase = vb + (size_t)(b * NH + h) * NS * NHD;

  // stage q into LDS (8 lanes x 16B)
  if (lane < 8) *(bf16x8*)(&ql[wave][lane * 8]) = *(const bf16x8*)(qrow + lane * 8);
  __syncthreads();

  // --- diagonal key j=i (always valid): lane = dim, full-wave reduce ---
  float sd = bf2f((short)ql[wave][lane]) * bf2f((short)kbase[(size_t)iv * NHD + lane]);
  for (int off = 1; off < 64; off <<= 1) sd += __shfl_xor(sd, off, 64);
  sd *= 0.125f;

  // --- 32 candidate keys, 2 lanes per key (half = 32 dims each) ---
  const int c = lane >> 1, half = lane & 1;
  int j, valid;
  if (c < 16) {
    j = i - NHWIN + c;  // window j = i-16 .. i-1
    valid = (j >= 0);
  } else {
    const int* rr = rand_idx + ((size_t)b * NS + iv) * NRC;
    const int cr = c - 16;
    j = rr[cr];
    valid = (j <= i - NHWIN - 1);  // causal AND strictly below window
    for (int cp = 0; cp < cr; cp++) valid &= (rr[cp] != j);  // first occurrence wins
  }
  const int jr = valid ? j : 0;
  float s = 0.f;
  {
    const u16* krow = kbase + (size_t)jr * NHD + half * 32;
    for (int c8 = 0; c8 < 4; c8++) {
      bf16x8 kv = *(const bf16x8*)(krow + c8 * 8);
      bf16x8 qv = *(const bf16x8*)(&ql[wave][half * 32 + c8 * 8]);
      for (int e = 0; e < 8; e++) s += bf2f(qv[e]) * bf2f(kv[e]);
    }
  }
  s += __shfl_xor(s, 1, 64);  // combine halves; both lanes of pair hold full dot
  s = valid ? s * 0.125f : -INFINITY;

  // --- softmax over {32 candidates} U {diag} ---
  float smax = s;
  for (int off = 1; off < 64; off <<= 1) smax = fmaxf(smax, __shfl_xor(smax, off, 64));
  smax = fmaxf(smax, sd);
  float p = valid ? __expf(s - smax) : 0.f;
  float pd = __expf(sd - smax);
  float pm = (half == 0) ? p : 0.f;
  for (int off = 1; off < 64; off <<= 1) pm += __shfl_xor(pm, off, 64);
  const float lsum = pm + pd;

  if (half == 0) {
    pl[wave][c] = p;
    jl[wave][c] = jr;
  }
  if (lane == 0) {
    pl[wave][32] = pd;
    jl[wave][32] = iv;
  }
  __syncthreads();

  // --- PV: lane = output dim; key index wave-uniform -> SGPR base via readfirstlane ---
  float o = 0.f;
  for (int jj = 0; jj < 33; jj++) {
    const int jk = __builtin_amdgcn_readfirstlane(jl[wave][jj]);
    const float pj = pl[wave][jj];
    o += pj * bf2f((short)vbase[(size_t)jk * NHD + lane]);
  }
  if (i >= 0)
    attnb[((size_t)(b * NS + i) * NH + h) * NHD + lane] = f2bf(o / lsum);
}

extern "C" void kernel_launch(void* const* d_in, const int* in_sizes, int n_in,
                              void* d_out, int out_size, void* d_ws, size_t ws_size,
                              hipStream_t stream) {
  const float* x = (const float*)d_in[0];
  const float* bq = (const float*)d_in[2];
  const float* bk = (const float*)d_in[4];
  const float* bv = (const float*)d_in[6];
  const float* bo = (const float*)d_in[8];
  const float* Ws1 = (const float*)d_in[9];
  const float* bs1 = (const float*)d_in[10];
  const float* Ws2 = (const float*)d_in[11];
  const int* rand_idx = (const int*)d_in[13];
  float* out = (float*)d_out;

  // workspace layout (~37 MB)
  char* p = (char*)d_ws;
  u16* wt = (u16*)p;         p += (size_t)4 * ND * ND * 2;         // 2 MB  [Wq^T;Wk^T;Wv^T;Wo^T] bf16
  u16* xb = (u16*)p;         p += (size_t)NB * NS * ND * 2;        // 4 MB x bf16 [4096,512]
  u16* qbuf = (u16*)p;       p += (size_t)NB * NH * NS * NHD * 2;  // 4 MB [B,H,S,HD]
  u16* kbuf = (u16*)p;       p += (size_t)NB * NH * NS * NHD * 2;  // 4 MB
  u16* vtbuf = (u16*)p;      p += (size_t)NB * NH * NHD * NS * 2;  // 4 MB [B,H,HD,S]
  u16* vbuf = (u16*)p;       p += (size_t)NB * NH * NS * NHD * 2;  // 4 MB [B,H,S,HD]
  u16* attnb = (u16*)p;      p += (size_t)NB * NS * ND * 2;        // 4 MB [B,S,H,HD]
  float* part = (float*)p;   p += (size_t)NB * NS * 4 * 4;         // 64 KB logit partials
  int* rowimp = (int*)p;     p += (size_t)NB * NS * 4;
  int* ilist = (int*)p;      p += (size_t)NB * NILIST * 4;
  int* nlist = (int*)p;      p += (size_t)NB * NSPAD * 4;
  float* pbuf = (float*)p;   // 10.8 MB partials

  // scorer + weight transpose + x conversion (one launch; scorer first - it gates the rank chain)
  csa_prep<<<dim3(1792), 256, 0, stream>>>((const float*)d_in[1], (const float*)d_in[3],
                                           (const float*)d_in[5], (const float*)d_in[7], wt,
                                           x, xb, Ws1, bs1, Ws2, part);
  csa_rank<<<dim3(NS / 8, NB), 256, 0, stream>>>(part, rowimp);

  // fused QKV projection (pure bf16 GEMM, head->XCD swizzled) + ilist compaction (blocks 768..769)
  csa_gemm_qkv<<<dim3(770), 256, 0, stream>>>(xb, wt, bq, bk, bv, qbuf, kbuf, vtbuf, vbuf,
                                              rowimp, ilist, nlist);

  // important-row attention (MFMA, 8-way split-K, head->XCD swizzled)
  csa_attn_imp<<<dim3(2560), 64, 0, stream>>>(qbuf, kbuf, vtbuf, ilist, pbuf);

  // sparse rows (per-wave, head->XCD swizzled) + imp-partial merge (blocks NSPB..NSPB+NMRG-1)
  csa_attn_sparse<<<dim3(NSPB + NMRG), 256, 0, stream>>>(qbuf, kbuf, vbuf, nlist, rand_idx,
                                                         pbuf, ilist, attnb);

  // output projection
  csa_gemm_out<<<dim3(64, 8), 256, 0, stream>>>(attnb, wt + 3 * (size_t)ND * ND, bo, out);
}

// Round 11
// 192.928 us; speedup vs baseline: 1.1286x; 1.0303x over previous
//
#include <hip/hip_runtime.h>
#include <math.h>

typedef unsigned short u16;
typedef unsigned int u32;
typedef unsigned long long u64;
typedef short bf16x8 __attribute__((ext_vector_type(8)));
typedef float f32x4 __attribute__((ext_vector_type(4)));

constexpr int NB = 2, NS = 2048, ND = 512, NH = 8, NHD = 64;
constexpr int NKTOP = 307, NHWIN = 16, NRC = 16;
constexpr int NILIST = 320;        // 20 tiles of 16 (padded with -1)
constexpr int NSPAR = NS - NKTOP;  // 1741 non-important rows (exact: rank is a permutation)
constexpr int NSPAD = 1744;        // padded to multiple of 4
constexpr int NCHUNK = 16;         // key-split factor for important-row attention
constexpr int LDSK64 = 72;         // 144B row stride for 64-k tiles
constexpr int PSTR = 72;           // P-tile row stride (16 rows x 64 keys)
constexpr int NSPB = (NSPAD / 4) * NH * NB;  // 6976 sparse blocks
constexpr int NMRG = NKTOP * NH * NB / 4;    // 1228 merge blocks (4 rows each; 4912 = 1228*4 exact)

__device__ __forceinline__ u16 f2bf(float f) {
  u32 u = __builtin_bit_cast(u32, f);
  u32 r = (u + 0x7FFFu + ((u >> 16) & 1u)) >> 16;  // RNE
  return (u16)r;
}
__device__ __forceinline__ float bf2f(short v) {
  return __builtin_bit_cast(float, (u32)(u16)v << 16);
}

// -------- fused prep: scorer (0..255) + weight transpose (256..767) + x cvt (768..1791) --------
// scorer: part[row][ny] = relu(x@Ws1+bs1).Ws2 over 64-col slice (fp32), K=64 staging.
// sigmoid and bs2 are strictly monotone / constant -> ranking on raw logits is identical.
__global__ __launch_bounds__(256) void csa_prep(const float* __restrict__ W0, const float* __restrict__ W1,
                                                const float* __restrict__ W2, const float* __restrict__ W3,
                                                u16* __restrict__ wt, const float* __restrict__ x,
                                                u16* __restrict__ xb, const float* __restrict__ Ws1,
                                                const float* __restrict__ bs1, const float* __restrict__ Ws2,
                                                float* __restrict__ part) {
  __shared__ float sh[2 * 64 * 68];  // 34.8 KB: scorer As+Bs (64-k stage); cvt tile (64x33) fits
  const int tid = threadIdx.x;
  if (blockIdx.x < 256) {
    // ---- scorer 64x64 tile, K=64 stages (half the barriers of K=32) ----
    const int m0 = (blockIdx.x & 63) * 64, n0 = (blockIdx.x >> 6) * 64;
    float(*As)[68] = (float(*)[68])sh;
    float(*Bs)[68] = (float(*)[68])(sh + 64 * 68);
    const int ty = tid >> 4, tx = tid & 15;
    float acc[4][4] = {};
    const int arow = tid & 63, aks = (tid >> 6) * 16;  // A: 64 rows x 64 k, 16 floats/thread
    const int bk = tid >> 2, bc = (tid & 3) * 16;      // B: 64 k x 64 n, 16 floats/thread
    for (int k0 = 0; k0 < ND; k0 += 64) {
      __syncthreads();
      for (int g = 0; g < 4; g++) {
        float4 a = *(const float4*)(&x[(size_t)(m0 + arow) * ND + k0 + aks + g * 4]);
        As[aks + g * 4 + 0][arow] = a.x;
        As[aks + g * 4 + 1][arow] = a.y;
        As[aks + g * 4 + 2][arow] = a.z;
        As[aks + g * 4 + 3][arow] = a.w;
      }
      for (int g = 0; g < 4; g++)
        *(float4*)(&Bs[bk][bc + g * 4]) = *(const float4*)(&Ws1[(size_t)(k0 + bk) * 256 + n0 + bc + g * 4]);
      __syncthreads();
      for (int k = 0; k < 64; k++) {
        float4 av = *(const float4*)(&As[k][ty * 4]);
        float4 bv = *(const float4*)(&Bs[k][tx * 4]);
        float aa[4] = {av.x, av.y, av.z, av.w};
        float bb[4] = {bv.x, bv.y, bv.z, bv.w};
        for (int i = 0; i < 4; i++)
          for (int j = 0; j < 4; j++)
            acc[i][j] += aa[i] * bb[j];
      }
    }
    float4 w2 = *(const float4*)(&Ws2[n0 + tx * 4]);
    float4 b1 = *(const float4*)(&bs1[n0 + tx * 4]);
    for (int i = 0; i < 4; i++) {
      float p = fmaxf(acc[i][0] + b1.x, 0.f) * w2.x + fmaxf(acc[i][1] + b1.y, 0.f) * w2.y +
                fmaxf(acc[i][2] + b1.z, 0.f) * w2.z + fmaxf(acc[i][3] + b1.w, 0.f) * w2.w;
      for (int off = 1; off < 16; off <<= 1) p += __shfl_xor(p, off, 64);
      if (tx == 0) part[(size_t)(m0 + ty * 4 + i) * 4 + (blockIdx.x >> 6)] = p;
    }
  } else if (blockIdx.x < 768) {
    // ---- weight transpose: W[K][N] fp32 -> Wt[N][K] bf16, 128B packed writes ----
    const int cb = blockIdx.x - 256;
    const int w = cb >> 7;
    const int kb = ((cb & 127) >> 4) * 64;
    const int nb = (cb & 15) * 32;
    const float* src = (w == 0) ? W0 : (w == 1) ? W1 : (w == 2) ? W2 : W3;
    float(*tile)[33] = (float(*)[33])sh;
    int tx = tid & 31, ty = tid >> 5;
    for (int i = ty; i < 64; i += 8) tile[i][tx] = src[(size_t)(kb + i) * ND + nb + tx];
    __syncthreads();
    u16* dst = wt + (size_t)w * ND * ND;
    for (int n = ty; n < 32; n += 8) {
      u32 pk = (u32)f2bf(tile[2 * tx][n]) | ((u32)f2bf(tile[2 * tx + 1][n]) << 16);
      *(u32*)(&dst[(size_t)(nb + n) * ND + kb + 2 * tx]) = pk;
    }
  } else {
    // ---- x fp32 -> bf16, one-time (removes 24x redundant conversion in qkv staging) ----
    const int i = ((blockIdx.x - 768) * 256 + tid) * 8;
    float4 v0 = *(const float4*)(x + i);
    float4 v1 = *(const float4*)(x + i + 4);
    u32 o0 = (u32)f2bf(v0.x) | ((u32)f2bf(v0.y) << 16);
    u32 o1 = (u32)f2bf(v0.z) | ((u32)f2bf(v0.w) << 16);
    u32 o2 = (u32)f2bf(v1.x) | ((u32)f2bf(v1.y) << 16);
    u32 o3 = (u32)f2bf(v1.z) | ((u32)f2bf(v1.w) << 16);
    uint4 o = {o0, o1, o2, o3};
    *(uint4*)(xb + i) = o;
  }
}

// -------- exact top-k on logits (lax.top_k tie semantics: lower index wins), wave per 2 rows --------
__global__ __launch_bounds__(256) void csa_rank(const float* __restrict__ part, int* __restrict__ rowimp) {
  __shared__ float vals[NS];
  const int b = blockIdx.y;
  {
    int t8 = threadIdx.x * 8;
    for (int e = 0; e < 8; e++) {
      float4 pp = *(const float4*)(&part[(size_t)(b * NS + t8 + e) * 4]);
      vals[t8 + e] = (pp.x + pp.y) + (pp.z + pp.w);  // fixed order -> deterministic
    }
  }
  __syncthreads();
  const int wave = threadIdx.x >> 6, lane = threadIdx.x & 63;
  const int s0 = blockIdx.x * 8 + wave * 2;  // two rows per wave
  const int s1 = s0 + 1;
  const float v0 = vals[s0], v1 = vals[s1];
  int r0 = 0, r1 = 0;
  for (int t = lane; t < NS; t += 64) {
    float u = vals[t];
    r0 += (int)((u > v0) | ((u == v0) & (t < s0)));
    r1 += (int)((u > v1) | ((u == v1) & (t < s1)));
  }
  for (int off = 1; off < 64; off <<= 1) {
    r0 += __shfl_xor(r0, off, 64);
    r1 += __shfl_xor(r1, off, 64);
  }
  if (lane == 0) {
    rowimp[b * NS + s0] = (r0 < NKTOP) ? 1 : 0;
    rowimp[b * NS + s1] = (r1 < NKTOP) ? 1 : 0;
  }
}

// -------- fused QKV projection (blocks 0..767) + row-list compaction (blocks 768..769) --------
// qkv: pure bf16 MFMA, 128x64 tile, K=64 stages, N=1536. 1-D grid, XCD swizzle: head = bid & 7.
// ilist: compact important rows (and complement) into sorted lists (depends on rank, runs here).
__global__ __launch_bounds__(256) void csa_gemm_qkv(const u16* __restrict__ xb, const u16* __restrict__ Bt,
                                                    const float* __restrict__ bq, const float* __restrict__ bk,
                                                    const float* __restrict__ bv, u16* __restrict__ qb,
                                                    u16* __restrict__ kb, u16* __restrict__ vtb,
                                                    u16* __restrict__ vb, const int* __restrict__ rowimp,
                                                    int* __restrict__ ilist, int* __restrict__ nlist) {
  __shared__ __attribute__((aligned(16))) u16 As[128 * LDSK64];  // 18.4 KB
  __shared__ __attribute__((aligned(16))) u16 Bs[64 * LDSK64];   // 9.2 KB
  const int tid = threadIdx.x;
  if (blockIdx.x >= 768) {
    // ---- ilist: prefix-sum compaction, one block per batch ----
    int* cs = (int*)As;
    const int b = blockIdx.x - 768;
    const int t = tid;
    int flags[8], sum = 0;
    for (int k = 0; k < 8; k++) {
      flags[k] = rowimp[b * NS + t * 8 + k];
      sum += flags[k];
    }
    cs[t] = sum;
    __syncthreads();
    for (int off = 1; off < 256; off <<= 1) {
      int v = (t >= off) ? cs[t - off] : 0;
      __syncthreads();
      cs[t] += v;
      __syncthreads();
    }
    int pos = cs[t] - sum;  // important rows before t*8
    for (int k = 0; k < 8; k++) {
      int r = t * 8 + k;
      if (flags[k]) ilist[b * NILIST + pos++] = r;
      else nlist[b * NSPAD + (r - pos)] = r;  // r - pos = non-important rows before r
    }
    if (t < NILIST - NKTOP) ilist[b * NILIST + NKTOP + t] = -1;
    if (t < NSPAD - NSPAR) nlist[b * NSPAD + NSPAR + t] = -1;
    return;
  }
  const int wave = tid >> 6, lane = tid & 63;
  const int quad = lane >> 4, col = lane & 15;
  const int hsw = blockIdx.x & 7;          // head (XCD pin)
  const int rest = blockIdx.x >> 3;        // 0..95
  const int w = rest >> 5;                 // 0=Q 1=K 2=V
  const int m0 = (rest & 31) * 128;
  const int n0 = (w * 8 + hsw) * 64;
  const f32x4 zf = {0.f, 0.f, 0.f, 0.f};
  f32x4 acc[2][4] = {{zf, zf, zf, zf}, {zf, zf, zf, zf}};
  const int sar = tid >> 1, sak = (tid & 1) * 32;  // A: 128 rows x 64 k, 32 u16/thread
  const int sbr = tid >> 2, sbk = (tid & 3) * 16;  // B: 64 rows x 64 k, 16 u16/thread
  for (int k0 = 0; k0 < ND; k0 += 64) {
    __syncthreads();
    {
      const u16* xp = &xb[(size_t)(m0 + sar) * ND + k0 + sak];
      u16* ap = &As[sar * LDSK64 + sak];
      *(uint4*)(ap) = *(const uint4*)(xp);
      *(uint4*)(ap + 8) = *(const uint4*)(xp + 8);
      *(uint4*)(ap + 16) = *(const uint4*)(xp + 16);
      *(uint4*)(ap + 24) = *(const uint4*)(xp + 24);
    }
    *(uint4*)(&Bs[sbr * LDSK64 + sbk]) = *(const uint4*)(&Bt[(size_t)(n0 + sbr) * ND + k0 + sbk]);
    *(uint4*)(&Bs[sbr * LDSK64 + sbk + 8]) = *(const uint4*)(&Bt[(size_t)(n0 + sbr) * ND + k0 + sbk + 8]);
    __syncthreads();
    bf16x8 af[2][2];
    for (int r = 0; r < 2; r++)
      for (int hh = 0; hh < 2; hh++)
        af[r][hh] = *(const bf16x8*)(&As[(wave * 32 + r * 16 + col) * LDSK64 + hh * 32 + quad * 8]);
    for (int c = 0; c < 4; c++) {
      bf16x8 b0 = *(const bf16x8*)(&Bs[(c * 16 + col) * LDSK64 + quad * 8]);
      bf16x8 b1 = *(const bf16x8*)(&Bs[(c * 16 + col) * LDSK64 + 32 + quad * 8]);
      acc[0][c] = __builtin_amdgcn_mfma_f32_16x16x32_bf16(af[0][0], b0, acc[0][c], 0, 0, 0);
      acc[0][c] = __builtin_amdgcn_mfma_f32_16x16x32_bf16(af[0][1], b1, acc[0][c], 0, 0, 0);
      acc[1][c] = __builtin_amdgcn_mfma_f32_16x16x32_bf16(af[1][0], b0, acc[1][c], 0, 0, 0);
      acc[1][c] = __builtin_amdgcn_mfma_f32_16x16x32_bf16(af[1][1], b1, acc[1][c], 0, 0, 0);
    }
  }
  const float* bias = (w == 0) ? bq : (w == 1) ? bk : bv;
  for (int c = 0; c < 4; c++) {
    const int ng = n0 + c * 16 + col;
    const int nn = ng & 511, hh = nn >> 6, hd = nn & 63;
    const float bvv = bias[nn];
    for (int r = 0; r < 2; r++) {
      for (int rr = 0; rr < 4; rr++) {
        const int m = m0 + wave * 32 + r * 16 + quad * 4 + rr;
        const int bb = m >> 11, s = m & (NS - 1);
        u16 v16 = f2bf(acc[r][c][rr] + bvv);
        if (w == 0) qb[((size_t)(bb * NH + hh) * NS + s) * NHD + hd] = v16;
        else if (w == 1) kb[((size_t)(bb * NH + hh) * NS + s) * NHD + hd] = v16;
        else {
          vtb[((size_t)(bb * NH + hh) * NHD + hd) * NS + s] = v16;
          vb[((size_t)(bb * NH + hh) * NS + s) * NHD + hd] = v16;
        }
      }
    }
  }
}

// -------- output projection: bf16 MFMA 64x64 tile, K=64 stages, fp32 out --------
__global__ __launch_bounds__(256) void csa_gemm_out(const u16* __restrict__ A, const u16* __restrict__ Bt,
                                                    const float* __restrict__ bias, float* __restrict__ outp) {
  __shared__ __attribute__((aligned(16))) u16 As[64 * LDSK64];
  __shared__ __attribute__((aligned(16))) u16 Bs[64 * LDSK64];
  const int tid = threadIdx.x;
  const int wave = tid >> 6, lane = tid & 63;
  const int quad = lane >> 4, col = lane & 15;
  const int m0 = blockIdx.x * 64;
  const int n0 = blockIdx.y * 64;
  const f32x4 zf = {0.f, 0.f, 0.f, 0.f};
  f32x4 acc[4] = {zf, zf, zf, zf};
  const int sr = tid >> 2, sk = (tid & 3) * 16;  // 64 rows x 64 k, 16 u16/thread
  for (int k0 = 0; k0 < ND; k0 += 64) {
    __syncthreads();
    *(uint4*)(&As[sr * LDSK64 + sk]) = *(const uint4*)(&A[(size_t)(m0 + sr) * ND + k0 + sk]);
    *(uint4*)(&As[sr * LDSK64 + sk + 8]) = *(const uint4*)(&A[(size_t)(m0 + sr) * ND + k0 + sk + 8]);
    *(uint4*)(&Bs[sr * LDSK64 + sk]) = *(const uint4*)(&Bt[(size_t)(n0 + sr) * ND + k0 + sk]);
    *(uint4*)(&Bs[sr * LDSK64 + sk + 8]) = *(const uint4*)(&Bt[(size_t)(n0 + sr) * ND + k0 + sk + 8]);
    __syncthreads();
    bf16x8 af0 = *(const bf16x8*)(&As[(wave * 16 + col) * LDSK64 + quad * 8]);
    bf16x8 af1 = *(const bf16x8*)(&As[(wave * 16 + col) * LDSK64 + 32 + quad * 8]);
    for (int nt = 0; nt < 4; nt++) {
      bf16x8 bf0 = *(const bf16x8*)(&Bs[(nt * 16 + col) * LDSK64 + quad * 8]);
      bf16x8 bf1 = *(const bf16x8*)(&Bs[(nt * 16 + col) * LDSK64 + 32 + quad * 8]);
      acc[nt] = __builtin_amdgcn_mfma_f32_16x16x32_bf16(af0, bf0, acc[nt], 0, 0, 0);
      acc[nt] = __builtin_amdgcn_mfma_f32_16x16x32_bf16(af1, bf1, acc[nt], 0, 0, 0);
    }
  }
  for (int nt = 0; nt < 4; nt++) {
    const int n = n0 + nt * 16 + col;
    const float bvv = bias[n];
    for (int r = 0; r < 4; r++) {
      const int m = m0 + wave * 16 + quad * 4 + r;
      outp[(size_t)m * ND + n] = acc[nt][r] + bvv;
    }
  }
}

// -------- important-row attention: gathered rows, pure causal, 16-way key-split, 64-key tiles ------
// 1-D grid, XCD swizzle: h = bid & 7 (K/V of head h stays in XCD-h L2).
// partials pbuf[((bh*16+chunk)*NILIST + row)*66] = {m, l, o[64] unnormalized}
__global__ __launch_bounds__(64) void csa_attn_imp(const u16* __restrict__ qb, const u16* __restrict__ kb,
                                                   const u16* __restrict__ vtb, const int* __restrict__ ilist,
                                                   float* __restrict__ pbuf) {
  const int lane = threadIdx.x;
  const int quad = lane >> 4, col = lane & 15;
  const int h = blockIdx.x & 7;         // XCD pin
  const int b = (blockIdx.x >> 3) & 1;
  const int rest = blockIdx.x >> 4;     // 0..(20*NCHUNK-1)
  const int qt = rest % (NILIST / 16);
  const int chunk = rest / (NILIST / 16);
  const int bh = b * NH + h;

  const int* il = ilist + b * NILIST;
  const u16* qptr = qb + (size_t)(b * NH + h) * NS * NHD;
  const u16* kptr = kb + (size_t)(b * NH + h) * NS * NHD;
  const u16* vptr = vtb + (size_t)(b * NH + h) * NHD * NS;

  const int iq = il[qt * 16 + col];
  const int qrow = (iq < 0) ? 0 : iq;
  bf16x8 qf0 = *(const bf16x8*)(qptr + qrow * NHD + quad * 8);
  bf16x8 qf1 = *(const bf16x8*)(qptr + qrow * NHD + 32 + quad * 8);

  const f32x4 zf = {0.f, 0.f, 0.f, 0.f};
  float m_r[4], l_r[4];
  f32x4 of[4];
  int irow[4];
  for (int r = 0; r < 4; r++) {
    m_r[r] = -INFINITY;
    l_r[r] = 0.f;
    irow[r] = il[qt * 16 + quad * 4 + r];  // -1 for padding rows
  }
  for (int n = 0; n < 4; n++) of[n] = zf;

  __shared__ __attribute__((aligned(16))) u16 Pl[16 * PSTR];

  const int max_i = il[(qt * 16 + 15 > NKTOP - 1) ? (NKTOP - 1) : (qt * 16 + 15)];
  const int ntiles = (max_i >> 6) + 1;  // 64-key tiles
  for (int t = chunk; t < ntiles; t += NCHUNK) {
    const int j0 = t * 64;
    f32x4 cg[4];
    for (int g = 0; g < 4; g++) {
      const int jb = j0 + g * 16;
      bf16x8 k0f = *(const bf16x8*)(kptr + (jb + col) * NHD + quad * 8);
      bf16x8 k1f = *(const bf16x8*)(kptr + (jb + col) * NHD + 32 + quad * 8);
      f32x4 c = zf;
      c = __builtin_amdgcn_mfma_f32_16x16x32_bf16(qf0, k0f, c, 0, 0, 0);
      c = __builtin_amdgcn_mfma_f32_16x16x32_bf16(qf1, k1f, c, 0, 0, 0);
      cg[g] = c;
    }
    float ps[4][4], alpha[4];
    for (int r = 0; r < 4; r++) {
      const int i = irow[r];
      float s[4];
      float vmax = -INFINITY;
      for (int g = 0; g < 4; g++) {
        s[g] = (j0 + g * 16 + col <= i) ? cg[g][r] * 0.125f : -INFINITY;
        vmax = fmaxf(vmax, s[g]);
      }
      for (int off = 1; off < 16; off <<= 1) vmax = fmaxf(vmax, __shfl_xor(vmax, off, 64));
      float newm = fmaxf(m_r[r], vmax);
      bool dead = (newm == -INFINITY);
      float a = dead ? 1.f : __expf(m_r[r] - newm);
      float psum = 0.f;
      for (int g = 0; g < 4; g++) {
        float p = dead ? 0.f : __expf(s[g] - newm);
        ps[r][g] = p;
        psum += p;
      }
      for (int off = 1; off < 16; off <<= 1) psum += __shfl_xor(psum, off, 64);
      m_r[r] = newm;
      l_r[r] = l_r[r] * a + psum;
      alpha[r] = a;
    }
    for (int n = 0; n < 4; n++)
      for (int r = 0; r < 4; r++) of[n][r] *= alpha[r];
    __syncthreads();
    for (int r = 0; r < 4; r++)
      for (int g = 0; g < 4; g++)
        Pl[(quad * 4 + r) * PSTR + g * 16 + col] = f2bf(ps[r][g]);
    __syncthreads();
    bf16x8 pf0 = *(const bf16x8*)(&Pl[col * PSTR + quad * 8]);
    bf16x8 pf1 = *(const bf16x8*)(&Pl[col * PSTR + 32 + quad * 8]);
    for (int vn = 0; vn < 4; vn++) {
      bf16x8 vf0 = *(const bf16x8*)(vptr + (size_t)(vn * 16 + col) * NS + j0 + quad * 8);
      bf16x8 vf1 = *(const bf16x8*)(vptr + (size_t)(vn * 16 + col) * NS + j0 + 32 + quad * 8);
      of[vn] = __builtin_amdgcn_mfma_f32_16x16x32_bf16(pf0, vf0, of[vn], 0, 0, 0);
      of[vn] = __builtin_amdgcn_mfma_f32_16x16x32_bf16(pf1, vf1, of[vn], 0, 0, 0);
    }
  }
  float* pr = pbuf + ((size_t)(bh * NCHUNK + chunk) * NILIST + qt * 16) * 66;
  for (int r = 0; r < 4; r++) {
    const int row = quad * 4 + r;
    if (col == 0) {
      pr[row * 66 + 0] = m_r[r];
      pr[row * 66 + 1] = l_r[r];
    }
    for (int vn = 0; vn < 4; vn++)
      pr[row * 66 + 2 + vn * 16 + col] = of[vn][r];
  }
}

// -------- fused: sparse-row attention (blocks 0..NSPB-1) + imp-partial merge (NSPB..NSPB+NMRG-1) ----
// sparse: non-important rows, 2 lanes/key + diag, 1 wave/(row,head); XCD swizzle h = bid & 7.
// merge: reads pbuf (written by csa_attn_imp, previous launch); disjoint attnb rows vs sparse.
__global__ __launch_bounds__(256) void csa_attn_sparse(const u16* __restrict__ qb, const u16* __restrict__ kb,
                                                       const u16* __restrict__ vb, const int* __restrict__ nlist,
                                                       const int* __restrict__ rand_idx,
                                                       const float* __restrict__ pbuf,
                                                       const int* __restrict__ ilist, u16* __restrict__ attnb) {
  __shared__ __attribute__((aligned(16))) u16 ql[4][64];
  __shared__ float pl[4][33];
  __shared__ int jl[4][33];
  const int wave = threadIdx.x >> 6, lane = threadIdx.x & 63;
  if (blockIdx.x >= NSPB) {
    // ---- merge important-row partials: 4 (kp,h,b) units per block, one per wave ----
    const int mu = (blockIdx.x - NSPB) * 4 + wave;  // 0..4911
    const int kp = mu % NKTOP;
    const int h = (mu / NKTOP) & 7;
    const int b = mu / (NKTOP * NH);
    const int z = b * NH + h;
    float mstar = -INFINITY;
    for (int c = 0; c < NCHUNK; c++)
      mstar = fmaxf(mstar, pbuf[((size_t)(z * NCHUNK + c) * NILIST + kp) * 66]);
    float lsum = 0.f, osum = 0.f;
    for (int c = 0; c < NCHUNK; c++) {
      const float* base = pbuf + ((size_t)(z * NCHUNK + c) * NILIST + kp) * 66;
      float mc = base[0];
      float w = (mc == -INFINITY) ? 0.f : __expf(mc - mstar);
      lsum += w * base[1];
      osum += w * base[2 + lane];
    }
    const int i = ilist[b * NILIST + kp];
    attnb[((size_t)(b * NS + i) * NH + h) * NHD + lane] = f2bf(osum / lsum);
    return;
  }
  const int h = blockIdx.x & 7;         // XCD pin
  const int b = (blockIdx.x >> 3) & 1;
  const int slot = (blockIdx.x >> 4) * 4 + wave;
  const int i = nlist[b * NSPAD + slot];  // -1 for the 3 pad slots
  const int iv = (i < 0) ? 0 : i;

  const u16* qrow = qb + ((size_t)(b * NH + h) * NS + iv) * NHD;
  const u16* kbase = kb + (size_t)(b * NH + h) * NS * NHD;
  const u16* vbase = vb + (size_t)(b * NH + h) * NS * NHD;

  // stage q into LDS (8 lanes x 16B)
  if (lane < 8) *(bf16x8*)(&ql[wave][lane * 8]) = *(const bf16x8*)(qrow + lane * 8);
  __syncthreads();

  // --- diagonal key j=i (always valid): lane = dim, full-wave reduce ---
  float sd = bf2f((short)ql[wave][lane]) * bf2f((short)kbase[(size_t)iv * NHD + lane]);
  for (int off = 1; off < 64; off <<= 1) sd += __shfl_xor(sd, off, 64);
  sd *= 0.125f;

  // --- 32 candidate keys, 2 lanes per key (half = 32 dims each) ---
  const int c = lane >> 1, half = lane & 1;
  int j, valid;
  if (c < 16) {
    j = i - NHWIN + c;  // window j = i-16 .. i-1
    valid = (j >= 0);
  } else {
    const int* rr = rand_idx + ((size_t)b * NS + iv) * NRC;
    const int cr = c - 16;
    j = rr[cr];
    valid = (j <= i - NHWIN - 1);  // causal AND strictly below window
    for (int cp = 0; cp < cr; cp++) valid &= (rr[cp] != j);  // first occurrence wins
  }
  const int jr = valid ? j : 0;
  float s = 0.f;
  {
    const u16* krow = kbase + (size_t)jr * NHD + half * 32;
    for (int c8 = 0; c8 < 4; c8++) {
      bf16x8 kv = *(const bf16x8*)(krow + c8 * 8);
      bf16x8 qv = *(const bf16x8*)(&ql[wave][half * 32 + c8 * 8]);
      for (int e = 0; e < 8; e++) s += bf2f(qv[e]) * bf2f(kv[e]);
    }
  }
  s += __shfl_xor(s, 1, 64);  // combine halves; both lanes of pair hold full dot
  s = valid ? s * 0.125f : -INFINITY;

  // --- softmax over {32 candidates} U {diag} ---
  float smax = s;
  for (int off = 1; off < 64; off <<= 1) smax = fmaxf(smax, __shfl_xor(smax, off, 64));
  smax = fmaxf(smax, sd);
  float p = valid ? __expf(s - smax) : 0.f;
  float pd = __expf(sd - smax);
  float pm = (half == 0) ? p : 0.f;
  for (int off = 1; off < 64; off <<= 1) pm += __shfl_xor(pm, off, 64);
  const float lsum = pm + pd;

  if (half == 0) {
    pl[wave][c] = p;
    jl[wave][c] = jr;
  }
  if (lane == 0) {
    pl[wave][32] = pd;
    jl[wave][32] = iv;
  }
  __syncthreads();

  // --- PV: lane = output dim; key index wave-uniform -> SGPR base via readfirstlane ---
  float o = 0.f;
  for (int jj = 0; jj < 33; jj++) {
    const int jk = __builtin_amdgcn_readfirstlane(jl[wave][jj]);
    const float pj = pl[wave][jj];
    o += pj * bf2f((short)vbase[(size_t)jk * NHD + lane]);
  }
  if (i >= 0)
    attnb[((size_t)(b * NS + i) * NH + h) * NHD + lane] = f2bf(o / lsum);
}

extern "C" void kernel_launch(void* const* d_in, const int* in_sizes, int n_in,
                              void* d_out, int out_size, void* d_ws, size_t ws_size,
                              hipStream_t stream) {
  const float* x = (const float*)d_in[0];
  const float* bq = (const float*)d_in[2];
  const float* bk = (const float*)d_in[4];
  const float* bv = (const float*)d_in[6];
  const float* bo = (const float*)d_in[8];
  const float* Ws1 = (const float*)d_in[9];
  const float* bs1 = (const float*)d_in[10];
  const float* Ws2 = (const float*)d_in[11];
  const int* rand_idx = (const int*)d_in[13];
  float* out = (float*)d_out;

  // workspace layout (~48 MB)
  char* p = (char*)d_ws;
  u16* wt = (u16*)p;         p += (size_t)4 * ND * ND * 2;         // 2 MB  [Wq^T;Wk^T;Wv^T;Wo^T] bf16
  u16* xb = (u16*)p;         p += (size_t)NB * NS * ND * 2;        // 4 MB x bf16 [4096,512]
  u16* qbuf = (u16*)p;       p += (size_t)NB * NH * NS * NHD * 2;  // 4 MB [B,H,S,HD]
  u16* kbuf = (u16*)p;       p += (size_t)NB * NH * NS * NHD * 2;  // 4 MB
  u16* vtbuf = (u16*)p;      p += (size_t)NB * NH * NHD * NS * 2;  // 4 MB [B,H,HD,S]
  u16* vbuf = (u16*)p;       p += (size_t)NB * NH * NS * NHD * 2;  // 4 MB [B,H,S,HD]
  u16* attnb = (u16*)p;      p += (size_t)NB * NS * ND * 2;        // 4 MB [B,S,H,HD]
  float* part = (float*)p;   p += (size_t)NB * NS * 4 * 4;         // 64 KB logit partials
  int* rowimp = (int*)p;     p += (size_t)NB * NS * 4;
  int* ilist = (int*)p;      p += (size_t)NB * NILIST * 4;
  int* nlist = (int*)p;      p += (size_t)NB * NSPAD * 4;
  float* pbuf = (float*)p;   // 21.6 MB partials (NCHUNK=16)

  // scorer + weight transpose + x conversion (one launch; scorer first - it gates the rank chain)
  csa_prep<<<dim3(1792), 256, 0, stream>>>((const float*)d_in[1], (const float*)d_in[3],
                                           (const float*)d_in[5], (const float*)d_in[7], wt,
                                           x, xb, Ws1, bs1, Ws2, part);
  csa_rank<<<dim3(NS / 8, NB), 256, 0, stream>>>(part, rowimp);

  // fused QKV projection (pure bf16 GEMM, head->XCD swizzled) + ilist compaction (blocks 768..769)
  csa_gemm_qkv<<<dim3(770), 256, 0, stream>>>(xb, wt, bq, bk, bv, qbuf, kbuf, vtbuf, vbuf,
                                              rowimp, ilist, nlist);

  // important-row attention (MFMA, 16-way split-K, head->XCD swizzled)
  csa_attn_imp<<<dim3((NILIST / 16) * NCHUNK * 16), 64, 0, stream>>>(qbuf, kbuf, vtbuf, ilist, pbuf);

  // sparse rows (per-wave, head->XCD swizzled) + imp-partial merge (blocks NSPB..NSPB+NMRG-1)
  csa_attn_sparse<<<dim3(NSPB + NMRG), 256, 0, stream>>>(qbuf, kbuf, vbuf, nlist, rand_idx,
                                                         pbuf, ilist, attnb);

  // output projection
  csa_gemm_out<<<dim3(64, 8), 256, 0, stream>>>(attnb, wt + 3 * (size_t)ND * ND, bo, out);
}